// Round 6
// baseline (256.031 us; speedup 1.0000x reference)
//
#include <hip/hip_runtime.h>
#include <math.h>

#define HID 128
#define TILE_R 64
#define XS_STRIDE 132      // fp32 staging stride (K1)
#define H0S_STRIDE 136     // bf16 h0 stride in shorts (K2): 272 B = 68 dwords == 4 mod 32 banks
#define DELTA 0.05f        // per-score qualify margin (R3-validated); worst-case bf16 err ~6e-3
#define CCAP 1024          // candidate cap (expected ~1-15)

typedef short bf16x8 __attribute__((ext_vector_type(8)));
typedef float f32x4 __attribute__((ext_vector_type(4)));

static __device__ __forceinline__ unsigned short f2bf(float f) {
    union { float f; unsigned u; } v; v.f = f;
    unsigned r = v.u + 0x7FFFu + ((v.u >> 16) & 1u);   // RNE
    return (unsigned short)(r >> 16);
}
static __device__ __forceinline__ float bflo(unsigned u) {
    union { unsigned u; float f; } v; v.u = u << 16; return v.f;
}
static __device__ __forceinline__ float bfhi(unsigned u) {
    union { unsigned u; float f; } v; v.u = u & 0xFFFF0000u; return v.f;
}

#define FMA4(avc, wv)                         \
    acc[r][0] = fmaf(avc, wv.x, acc[r][0]);   \
    acc[r][1] = fmaf(avc, wv.y, acc[r][1]);   \
    acc[r][2] = fmaf(avc, wv.z, acc[r][2]);   \
    acc[r][3] = fmaf(avc, wv.w, acc[r][3]);

// ---------------------------------------------------------------------------
// K1: g[128] = x_graph @ W0[0:256] + b0 (fp32, exact — rescue depends on it)
//     Pbf = bf16( [x_m @ W0[256:384] ; x_job @ W0[384:512]] )
//     W1T[n*128+k] = bf16(W1[k][n])   (MFMA B-fragment friendly)
// ---------------------------------------------------------------------------
__global__ __launch_bounds__(256, 4) void precompute_kernel(
    const float* __restrict__ x_graph,
    const float* __restrict__ x_m,
    const float* __restrict__ x_job,
    const float* __restrict__ W0,
    const float* __restrict__ b0,
    const float* __restrict__ W1,
    float* __restrict__ g,
    unsigned short* __restrict__ Pbf,
    unsigned short* __restrict__ W1T,
    int M, int J, int aTiles, int bTiles)
{
    const int t = threadIdx.x;
    const int bid = blockIdx.x;

    if (bid == 0) {
        __shared__ float xg[2 * HID];
        if (t < HID) { xg[t] = x_graph[t]; xg[t + HID] = x_graph[t + HID]; }
        __syncthreads();
        if (t < HID) {
            float acc = b0[t];
            #pragma unroll 8
            for (int k = 0; k < 2 * HID; ++k)
                acc = fmaf(xg[k], W0[k * HID + t], acc);
            g[t] = acc;
        }
        return;
    }
    if (bid == 1 + aTiles + bTiles) {
        for (int e = t; e < HID * HID; e += 256) {
            int n = e >> 7, k = e & 127;
            W1T[e] = f2bf(W1[k * HID + n]);
        }
        return;
    }

    const int tb = bid - 1;
    const float* X;
    const float* W;
    int r0, nr, dstBase;
    if (tb < aTiles) {
        r0 = tb * TILE_R;
        nr = min(TILE_R, M - r0);
        X = x_m + (size_t)r0 * HID;
        W = W0 + 2 * HID * HID;
        dstBase = r0;
    } else {
        int jb = tb - aTiles;
        r0 = jb * TILE_R;
        nr = min(TILE_R, J - r0);
        X = x_job + (size_t)r0 * HID;
        W = W0 + 3 * HID * HID;
        dstBase = M + r0;
    }

    __shared__ float xs[TILE_R * XS_STRIDE];
    {
        int row = t >> 2;
        int q = t & 3;
        #pragma unroll
        for (int u = 0; u < 8; ++u) {
            int c = q * 32 + u * 4;
            float4 v = (row < nr) ? *(const float4*)(X + row * HID + c)
                                  : make_float4(0.f, 0.f, 0.f, 0.f);
            *(float4*)&xs[row * XS_STRIDE + c] = v;
        }
    }
    __syncthreads();

    const int w = t >> 6;
    const int l = t & 63;
    const int tc = l & 7;
    const int tr = l >> 3;
    const int c0 = w * 32 + tc * 4;

    float acc[8][4];
    #pragma unroll
    for (int r = 0; r < 8; ++r)
        #pragma unroll
        for (int c = 0; c < 4; ++c) acc[r][c] = 0.0f;

    #pragma unroll 2
    for (int k0 = 0; k0 < HID; k0 += 4) {
        float4 w0v = *(const float4*)(W + (k0 + 0) * HID + c0);
        float4 w1v = *(const float4*)(W + (k0 + 1) * HID + c0);
        float4 w2m = *(const float4*)(W + (k0 + 2) * HID + c0);
        float4 w3v = *(const float4*)(W + (k0 + 3) * HID + c0);
        #pragma unroll
        for (int r = 0; r < 8; ++r) {
            float4 a = *(const float4*)&xs[(r * 8 + tr) * XS_STRIDE + k0];
            FMA4(a.x, w0v)
            FMA4(a.y, w1v)
            FMA4(a.z, w2m)
            FMA4(a.w, w3v)
        }
    }

    #pragma unroll
    for (int r = 0; r < 8; ++r) {
        int row = r * 8 + tr;
        if (row < nr) {
            unsigned lo0 = (unsigned)f2bf(acc[r][0]) | ((unsigned)f2bf(acc[r][1]) << 16);
            unsigned lo1 = (unsigned)f2bf(acc[r][2]) | ((unsigned)f2bf(acc[r][3]) << 16);
            uint2 pk = make_uint2(lo0, lo1);
            *(uint2*)(Pbf + (size_t)(dstBase + row) * HID + c0) = pk;
        }
    }
}

// ---------------------------------------------------------------------------
// K2: per 64-row tile: bf16 h0 staged in LDS, h1 via mfma_f32_16x16x32_bf16,
//     fused relu+b1 + W2 dot -> per-row score -> scores[] + per-block softmax
//     partial. No global atomics / fences (R3 lesson: fence tail ~106 us).
// ---------------------------------------------------------------------------
__global__ __launch_bounds__(256, 4) void main_kernel(
    const int* __restrict__ m_ids,
    const int* __restrict__ job_idx,
    const float* __restrict__ b1,
    const float* __restrict__ W2,
    const float* __restrict__ b2,
    const float* __restrict__ g,
    const unsigned short* __restrict__ Pbf,
    const unsigned short* __restrict__ W1T,
    float* __restrict__ scores,
    float4* __restrict__ partials,
    int N, int M)
{
    __shared__ __align__(16) short h0s[TILE_R * H0S_STRIDE];
    __shared__ float sred[TILE_R];

    const int t = threadIdx.x;
    const int row0 = blockIdx.x * TILE_R;

    // ---- stage h0 (bf16): thread t -> row t/4, 32-col quarter t%4 ----
    {
        int row = t >> 2;
        int q = t & 3;
        int grow = row0 + row;
        int gr = (grow < N) ? grow : (N - 1);
        int m = m_ids[gr];
        int j = job_idx[gr];
        const unsigned short* pm = Pbf + (size_t)m * HID + q * 32;
        const unsigned short* pj = Pbf + (size_t)(M + j) * HID + q * 32;
        const float* gp = g + q * 32;
        short* dst = &h0s[row * H0S_STRIDE + q * 32];
        #pragma unroll
        for (int u = 0; u < 4; ++u) {
            uint4 mv = *(const uint4*)(pm + u * 8);
            uint4 jv = *(const uint4*)(pj + u * 8);
            float4 g0 = *(const float4*)(gp + u * 8);
            float4 g1 = *(const float4*)(gp + u * 8 + 4);
            float h0v = fmaxf(bflo(mv.x) + bflo(jv.x) + g0.x, 0.f);
            float h1v = fmaxf(bfhi(mv.x) + bfhi(jv.x) + g0.y, 0.f);
            float h2v = fmaxf(bflo(mv.y) + bflo(jv.y) + g0.z, 0.f);
            float h3v = fmaxf(bfhi(mv.y) + bfhi(jv.y) + g0.w, 0.f);
            float h4v = fmaxf(bflo(mv.z) + bflo(jv.z) + g1.x, 0.f);
            float h5v = fmaxf(bfhi(mv.z) + bfhi(jv.z) + g1.y, 0.f);
            float h6v = fmaxf(bflo(mv.w) + bflo(jv.w) + g1.z, 0.f);
            float h7v = fmaxf(bfhi(mv.w) + bfhi(jv.w) + g1.w, 0.f);
            uint4 pk;
            pk.x = (unsigned)f2bf(h0v) | ((unsigned)f2bf(h1v) << 16);
            pk.y = (unsigned)f2bf(h2v) | ((unsigned)f2bf(h3v) << 16);
            pk.z = (unsigned)f2bf(h4v) | ((unsigned)f2bf(h5v) << 16);
            pk.w = (unsigned)f2bf(h6v) | ((unsigned)f2bf(h7v) << 16);
            *(uint4*)(dst + u * 8) = pk;
        }
    }
    __syncthreads();

    // ---- MFMA: wave w computes rows [w*16, w*16+16) x cols [0,128) ----
    const int l = t & 63;
    const int w = t >> 6;
    const int quad = l >> 4;
    const int mrow = l & 15;

    bf16x8 af[4];
    const short* ab = &h0s[(w * 16 + mrow) * H0S_STRIDE + quad * 8];
    #pragma unroll
    for (int kc = 0; kc < 4; ++kc)
        af[kc] = *(const bf16x8*)(ab + kc * 32);

    f32x4 acc[8];
    #pragma unroll
    for (int nt = 0; nt < 8; ++nt) {
        f32x4 z = {0.f, 0.f, 0.f, 0.f};
        acc[nt] = z;
    }

    const unsigned short* bb = W1T + (size_t)mrow * HID + quad * 8;
    #pragma unroll
    for (int nt = 0; nt < 8; ++nt) {
        #pragma unroll
        for (int kc = 0; kc < 4; ++kc) {
            bf16x8 bfr = *(const bf16x8*)(bb + nt * 16 * HID + kc * 32);
            acc[nt] = __builtin_amdgcn_mfma_f32_16x16x32_bf16(af[kc], bfr, acc[nt], 0, 0, 0);
        }
    }

    // ---- epilogue: relu+b1, dot W2; reduce across the 16 col-lanes ----
    float p0 = 0.f, p1 = 0.f, p2 = 0.f, p3 = 0.f;
    #pragma unroll
    for (int nt = 0; nt < 8; ++nt) {
        int c = nt * 16 + mrow;
        float b1v = b1[c], w2v = W2[c];
        p0 += fmaxf(acc[nt][0] + b1v, 0.f) * w2v;
        p1 += fmaxf(acc[nt][1] + b1v, 0.f) * w2v;
        p2 += fmaxf(acc[nt][2] + b1v, 0.f) * w2v;
        p3 += fmaxf(acc[nt][3] + b1v, 0.f) * w2v;
    }
    #pragma unroll
    for (int off = 1; off < 16; off <<= 1) {
        p0 += __shfl_xor(p0, off);
        p1 += __shfl_xor(p1, off);
        p2 += __shfl_xor(p2, off);
        p3 += __shfl_xor(p3, off);
    }
    if (mrow == 0) {
        int rb = w * 16 + quad * 4;
        sred[rb + 0] = p0;
        sred[rb + 1] = p1;
        sred[rb + 2] = p2;
        sred[rb + 3] = p3;
    }
    __syncthreads();

    // ---- wave 0: scores + per-block online-softmax partial over 64 rows ----
    if (t < 64) {
        int grow = row0 + t;
        float s = sred[t] + b2[0];
        if (grow < N) scores[grow] = s;
        else s = -1e30f;               // finite sentinel: exp->0, NaN-free

        float mmax = s;
        int midx = grow;
        #pragma unroll
        for (int off = 1; off < 64; off <<= 1) {
            float om = __shfl_xor(mmax, off);
            int oi = __shfl_xor(midx, off);
            if (om > mmax || (om == mmax && oi < midx)) { mmax = om; midx = oi; }
        }
        float d = s - mmax;
        float e = expf(d);
        float z = e;
        float ss = d * e;
        #pragma unroll
        for (int off = 1; off < 64; off <<= 1) {
            z += __shfl_xor(z, off);
            ss += __shfl_xor(ss, off);
        }
        if (t == 0)
            partials[blockIdx.x] = make_float4(mmax, z, ss, (float)midx);
    }
}

// ---------------------------------------------------------------------------
__device__ inline void sm_merge(float& am, float& az, float& ass, int& ai,
                                float bm, float bz, float bss, int bi)
{
    if (bm > am || (bm == am && bi < ai)) {
        float tm = am, tz = az, ts = ass; int ti = ai;
        am = bm; az = bz; ass = bss; ai = bi;
        bm = tm; bz = tz; bss = ts; bi = ti;
    }
    float f = expf(bm - am);
    az += bz * f;
    ass += (bss + (bm - am) * bz) * f;
}

// ---------------------------------------------------------------------------
// K3 (single block, 1024 thr):
//   1) merge partials -> mhat, Z, SS; out[3] = entropy           (R2-validated)
//   2) PER-SCORE candidates: scores[i] >= mhat - DELTA           (R3-validated
//      criterion; R4/R5 failed because per-BLOCK lists overflowed their cap
//      and the LDS-atomic arrival order picked an arbitrary subset)
//   3) exact fp32 rescore, one wave per candidate, registers + __shfl only
//   4) 16-way merge, min-idx tie-break (np.argmax first-occurrence).
// ---------------------------------------------------------------------------
__global__ __launch_bounds__(1024) void final_kernel(
    const float4* __restrict__ partials, int nparts,
    const float* __restrict__ scores,
    const int* __restrict__ m_ids,
    const int* __restrict__ job_idx,
    const float* __restrict__ x_m,
    const float* __restrict__ x_job,
    const float* __restrict__ W0,
    const float* __restrict__ W1,
    const float* __restrict__ b1,
    const float* __restrict__ W2,
    const float* __restrict__ b2,
    const float* __restrict__ g,
    float* __restrict__ out,
    int N)
{
    __shared__ float4 wred[16];
    __shared__ int widx[16];
    __shared__ float stats[2];          // mhat, Z
    __shared__ int cand[CCAP];
    __shared__ int ncand;
    __shared__ float rs[16];
    __shared__ int ri[16];

    const int t = threadIdx.x;
    const int w = t >> 6;
    const int l = t & 63;

    // ---- 1) merge partials ----
    float m = -1e30f, z = 0.f, ss = 0.f;
    int idx = 0x7fffffff;
    for (int i = t; i < nparts; i += 1024) {
        float4 p = partials[i];
        sm_merge(m, z, ss, idx, p.x, p.y, p.z, (int)p.w);
    }
    #pragma unroll
    for (int off = 1; off < 64; off <<= 1) {
        float om = __shfl_xor(m, off);
        float oz = __shfl_xor(z, off);
        float os = __shfl_xor(ss, off);
        int oi = __shfl_xor(idx, off);
        sm_merge(m, z, ss, idx, om, oz, os, oi);
    }
    if (l == 0) { wred[w] = make_float4(m, z, ss, 0.f); widx[w] = idx; }
    if (t == 0) ncand = 0;
    __syncthreads();
    if (t == 0) {
        for (int i = 1; i < 16; ++i)
            sm_merge(m, z, ss, idx, wred[i].x, wred[i].y, wred[i].z, widx[i]);
        out[3] = logf(z) - ss / z;      // entropy
        stats[0] = m; stats[1] = z;
    }
    __syncthreads();
    const float mhat = stats[0];
    const float cut = mhat - DELTA;

    // ---- 2) per-score candidate scan (coalesced, 196 iters) ----
    for (int i = t; i < N; i += 1024) {
        if (scores[i] >= cut) {
            int p = atomicAdd(&ncand, 1);   // LDS atomic — block-local
            if (p < CCAP) cand[p] = i;
        }
    }
    __syncthreads();
    const int nc = min(ncand, CCAP);

    // ---- 3) exact rescore: wave w handles candidates w, w+16, ... ----
    float bs = -1e30f;
    int bi = 0x7fffffff;
    for (int c = w; c < nc; c += 16) {
        int gr = cand[c];
        int mm = m_ids[gr];
        int jj = job_idx[gr];
        const float* xm = x_m + (size_t)mm * HID;
        const float* xj = x_job + (size_t)jj * HID;
        const float* wm = W0 + 2 * HID * HID;
        const float* wj = W0 + 3 * HID * HID;
        float a0 = g[l], a1 = g[l + 64];
        for (int k = 0; k < HID; ++k) {
            float xmk = xm[k];
            float xjk = xj[k];
            a0 = fmaf(xmk, wm[k * HID + l], a0);
            a1 = fmaf(xmk, wm[k * HID + l + 64], a1);
            a0 = fmaf(xjk, wj[k * HID + l], a0);
            a1 = fmaf(xjk, wj[k * HID + l + 64], a1);
        }
        a0 = fmaxf(a0, 0.f);            // lane l holds h0[l], h0[l+64]
        a1 = fmaxf(a1, 0.f);
        float acc0 = 0.f, acc1 = 0.f;   // h1 pre-act [l], [l+64]
        for (int k = 0; k < 64; ++k) {
            float h = __shfl(a0, k);    // broadcast h0[k] — register-only
            acc0 = fmaf(h, W1[k * HID + l], acc0);
            acc1 = fmaf(h, W1[k * HID + l + 64], acc1);
        }
        for (int k = 0; k < 64; ++k) {
            float h = __shfl(a1, k);    // broadcast h0[k+64]
            acc0 = fmaf(h, W1[(k + 64) * HID + l], acc0);
            acc1 = fmaf(h, W1[(k + 64) * HID + l + 64], acc1);
        }
        float p = fmaxf(acc0 + b1[l], 0.f) * W2[l]
                + fmaxf(acc1 + b1[l + 64], 0.f) * W2[l + 64];
        #pragma unroll
        for (int off = 1; off < 64; off <<= 1)
            p += __shfl_xor(p, off);
        float s = p + b2[0];
        if (s > bs || (s == bs && gr < bi)) { bs = s; bi = gr; }
    }
    if (l == 0) { rs[w] = bs; ri[w] = bi; }
    __syncthreads();

    // ---- 4) winner ----
    if (t == 0) {
        float best = rs[0];
        int bwin = ri[0];
        for (int i = 1; i < 16; ++i) {
            if (rs[i] > best || (rs[i] == best && ri[i] < bwin)) {
                best = rs[i]; bwin = ri[i];
            }
        }
        float Z = stats[1];
        out[0] = (float)bwin;
        out[1] = expf(best - mhat) / Z;
        out[2] = (best - mhat) - logf(Z);
    }
}

// ---------------------------------------------------------------------------
extern "C" void kernel_launch(void* const* d_in, const int* in_sizes, int n_in,
                              void* d_out, int out_size, void* d_ws, size_t ws_size,
                              hipStream_t stream)
{
    const float* x_graph = (const float*)d_in[0];
    const float* x_m     = (const float*)d_in[1];
    const float* x_job   = (const float*)d_in[2];
    const int*   m_ids   = (const int*)d_in[3];
    const int*   job_idx = (const int*)d_in[4];
    const float* W0      = (const float*)d_in[5];
    const float* b0      = (const float*)d_in[6];
    const float* W1      = (const float*)d_in[7];
    const float* b1      = (const float*)d_in[8];
    const float* W2      = (const float*)d_in[9];
    const float* b2      = (const float*)d_in[10];
    float* out = (float*)d_out;

    const int N = in_sizes[3];
    const int M = in_sizes[1] / HID;
    const int J = in_sizes[2] / HID;

    const int tiles = (N + TILE_R - 1) / TILE_R;         // 3125
    const int aTiles = (M + TILE_R - 1) / TILE_R;        // 16
    const int bTiles = (J + TILE_R - 1) / TILE_R;        // 79

    // ws layout (all segments 16-B aligned):
    float* ws = (float*)d_ws;
    float* g = ws;                                        // 128 f
    float* scores = ws + HID;                             // N f
    float4* partials = (float4*)(scores + N);             // tiles f4
    unsigned short* W1T = (unsigned short*)(partials + tiles);  // HID*HID shorts
    unsigned short* Pbf = W1T + HID * HID;                // (M+J)*HID shorts

    precompute_kernel<<<1 + aTiles + bTiles + 1, 256, 0, stream>>>(
        x_graph, x_m, x_job, W0, b0, W1, g, Pbf, W1T, M, J, aTiles, bTiles);
    main_kernel<<<tiles, 256, 0, stream>>>(
        m_ids, job_idx, b1, W2, b2, g, Pbf, W1T, scores, partials, N, M);
    final_kernel<<<1, 1024, 0, stream>>>(
        partials, tiles, scores, m_ids, job_idx, x_m, x_job, W0, W1, b1, W2, b2,
        g, out, N);
}

// Round 7
// 189.257 us; speedup vs baseline: 1.3528x; 1.3528x over previous
//
#include <hip/hip_runtime.h>
#include <math.h>

#define HID 128
#define TILE_R 64
#define XS_STRIDE 132      // fp32 staging stride (K1)
#define H0S_STRIDE 136     // bf16 h0 stride in shorts (K2): 272 B = 68 dwords == 4 mod 32 banks
#define DELTA 0.05f        // per-score qualify margin (R3/R6-validated)

typedef short bf16x8 __attribute__((ext_vector_type(8)));
typedef float f32x4 __attribute__((ext_vector_type(4)));

static __device__ __forceinline__ unsigned short f2bf(float f) {
    union { float f; unsigned u; } v; v.f = f;
    unsigned r = v.u + 0x7FFFu + ((v.u >> 16) & 1u);   // RNE
    return (unsigned short)(r >> 16);
}
static __device__ __forceinline__ float bflo(unsigned u) {
    union { unsigned u; float f; } v; v.u = u << 16; return v.f;
}
static __device__ __forceinline__ float bfhi(unsigned u) {
    union { unsigned u; float f; } v; v.u = u & 0xFFFF0000u; return v.f;
}

#define FMA4(avc, wv)                         \
    acc[r][0] = fmaf(avc, wv.x, acc[r][0]);   \
    acc[r][1] = fmaf(avc, wv.y, acc[r][1]);   \
    acc[r][2] = fmaf(avc, wv.z, acc[r][2]);   \
    acc[r][3] = fmaf(avc, wv.w, acc[r][3]);

// ---------------------------------------------------------------------------
// K1: g[128] = x_graph @ W0[0:256] + b0 (fp32, exact)
//     Pbf = bf16( [x_m @ W0[256:384] ; x_job @ W0[384:512]] )
//     W1T[n*128+k] = bf16(W1[k][n])
// ---------------------------------------------------------------------------
__global__ __launch_bounds__(256, 4) void precompute_kernel(
    const float* __restrict__ x_graph,
    const float* __restrict__ x_m,
    const float* __restrict__ x_job,
    const float* __restrict__ W0,
    const float* __restrict__ b0,
    const float* __restrict__ W1,
    float* __restrict__ g,
    unsigned short* __restrict__ Pbf,
    unsigned short* __restrict__ W1T,
    int M, int J, int aTiles, int bTiles)
{
    const int t = threadIdx.x;
    const int bid = blockIdx.x;

    if (bid == 0) {
        __shared__ float xg[2 * HID];
        if (t < HID) { xg[t] = x_graph[t]; xg[t + HID] = x_graph[t + HID]; }
        __syncthreads();
        if (t < HID) {
            float acc = b0[t];
            #pragma unroll 8
            for (int k = 0; k < 2 * HID; ++k)
                acc = fmaf(xg[k], W0[k * HID + t], acc);
            g[t] = acc;
        }
        return;
    }
    if (bid == 1 + aTiles + bTiles) {
        for (int e = t; e < HID * HID; e += 256) {
            int n = e >> 7, k = e & 127;
            W1T[e] = f2bf(W1[k * HID + n]);
        }
        return;
    }

    const int tb = bid - 1;
    const float* X;
    const float* W;
    int r0, nr, dstBase;
    if (tb < aTiles) {
        r0 = tb * TILE_R;
        nr = min(TILE_R, M - r0);
        X = x_m + (size_t)r0 * HID;
        W = W0 + 2 * HID * HID;
        dstBase = r0;
    } else {
        int jb = tb - aTiles;
        r0 = jb * TILE_R;
        nr = min(TILE_R, J - r0);
        X = x_job + (size_t)r0 * HID;
        W = W0 + 3 * HID * HID;
        dstBase = M + r0;
    }

    __shared__ float xs[TILE_R * XS_STRIDE];
    {
        int row = t >> 2;
        int q = t & 3;
        #pragma unroll
        for (int u = 0; u < 8; ++u) {
            int c = q * 32 + u * 4;
            float4 v = (row < nr) ? *(const float4*)(X + row * HID + c)
                                  : make_float4(0.f, 0.f, 0.f, 0.f);
            *(float4*)&xs[row * XS_STRIDE + c] = v;
        }
    }
    __syncthreads();

    const int w = t >> 6;
    const int l = t & 63;
    const int tc = l & 7;
    const int tr = l >> 3;
    const int c0 = w * 32 + tc * 4;

    float acc[8][4];
    #pragma unroll
    for (int r = 0; r < 8; ++r)
        #pragma unroll
        for (int c = 0; c < 4; ++c) acc[r][c] = 0.0f;

    #pragma unroll 2
    for (int k0 = 0; k0 < HID; k0 += 4) {
        float4 w0v = *(const float4*)(W + (k0 + 0) * HID + c0);
        float4 w1v = *(const float4*)(W + (k0 + 1) * HID + c0);
        float4 w2m = *(const float4*)(W + (k0 + 2) * HID + c0);
        float4 w3v = *(const float4*)(W + (k0 + 3) * HID + c0);
        #pragma unroll
        for (int r = 0; r < 8; ++r) {
            float4 a = *(const float4*)&xs[(r * 8 + tr) * XS_STRIDE + k0];
            FMA4(a.x, w0v)
            FMA4(a.y, w1v)
            FMA4(a.z, w2m)
            FMA4(a.w, w3v)
        }
    }

    #pragma unroll
    for (int r = 0; r < 8; ++r) {
        int row = r * 8 + tr;
        if (row < nr) {
            unsigned lo0 = (unsigned)f2bf(acc[r][0]) | ((unsigned)f2bf(acc[r][1]) << 16);
            unsigned lo1 = (unsigned)f2bf(acc[r][2]) | ((unsigned)f2bf(acc[r][3]) << 16);
            uint2 pk = make_uint2(lo0, lo1);
            *(uint2*)(Pbf + (size_t)(dstBase + row) * HID + c0) = pk;
        }
    }
}

// ---------------------------------------------------------------------------
// K2: per 64-row tile: bf16 h0 in LDS, h1 via mfma_f32_16x16x32_bf16,
//     fused relu+b1 + W2 dot -> scores[] + per-block softmax partial.
//     No global atomics/fences.
// ---------------------------------------------------------------------------
__global__ __launch_bounds__(256, 4) void main_kernel(
    const int* __restrict__ m_ids,
    const int* __restrict__ job_idx,
    const float* __restrict__ b1,
    const float* __restrict__ W2,
    const float* __restrict__ b2,
    const float* __restrict__ g,
    const unsigned short* __restrict__ Pbf,
    const unsigned short* __restrict__ W1T,
    float* __restrict__ scores,
    float4* __restrict__ partials,
    int N, int M)
{
    __shared__ __align__(16) short h0s[TILE_R * H0S_STRIDE];
    __shared__ float sred[TILE_R];

    const int t = threadIdx.x;
    const int row0 = blockIdx.x * TILE_R;

    {
        int row = t >> 2;
        int q = t & 3;
        int grow = row0 + row;
        int gr = (grow < N) ? grow : (N - 1);
        int m = m_ids[gr];
        int j = job_idx[gr];
        const unsigned short* pm = Pbf + (size_t)m * HID + q * 32;
        const unsigned short* pj = Pbf + (size_t)(M + j) * HID + q * 32;
        const float* gp = g + q * 32;
        short* dst = &h0s[row * H0S_STRIDE + q * 32];
        #pragma unroll
        for (int u = 0; u < 4; ++u) {
            uint4 mv = *(const uint4*)(pm + u * 8);
            uint4 jv = *(const uint4*)(pj + u * 8);
            float4 g0 = *(const float4*)(gp + u * 8);
            float4 g1 = *(const float4*)(gp + u * 8 + 4);
            float h0v = fmaxf(bflo(mv.x) + bflo(jv.x) + g0.x, 0.f);
            float h1v = fmaxf(bfhi(mv.x) + bfhi(jv.x) + g0.y, 0.f);
            float h2v = fmaxf(bflo(mv.y) + bflo(jv.y) + g0.z, 0.f);
            float h3v = fmaxf(bfhi(mv.y) + bfhi(jv.y) + g0.w, 0.f);
            float h4v = fmaxf(bflo(mv.z) + bflo(jv.z) + g1.x, 0.f);
            float h5v = fmaxf(bfhi(mv.z) + bfhi(jv.z) + g1.y, 0.f);
            float h6v = fmaxf(bflo(mv.w) + bflo(jv.w) + g1.z, 0.f);
            float h7v = fmaxf(bfhi(mv.w) + bfhi(jv.w) + g1.w, 0.f);
            uint4 pk;
            pk.x = (unsigned)f2bf(h0v) | ((unsigned)f2bf(h1v) << 16);
            pk.y = (unsigned)f2bf(h2v) | ((unsigned)f2bf(h3v) << 16);
            pk.z = (unsigned)f2bf(h4v) | ((unsigned)f2bf(h5v) << 16);
            pk.w = (unsigned)f2bf(h6v) | ((unsigned)f2bf(h7v) << 16);
            *(uint4*)(dst + u * 8) = pk;
        }
    }
    __syncthreads();

    const int l = t & 63;
    const int w = t >> 6;
    const int quad = l >> 4;
    const int mrow = l & 15;

    bf16x8 af[4];
    const short* ab = &h0s[(w * 16 + mrow) * H0S_STRIDE + quad * 8];
    #pragma unroll
    for (int kc = 0; kc < 4; ++kc)
        af[kc] = *(const bf16x8*)(ab + kc * 32);

    f32x4 acc[8];
    #pragma unroll
    for (int nt = 0; nt < 8; ++nt) {
        f32x4 z = {0.f, 0.f, 0.f, 0.f};
        acc[nt] = z;
    }

    const unsigned short* bb = W1T + (size_t)mrow * HID + quad * 8;
    #pragma unroll
    for (int nt = 0; nt < 8; ++nt) {
        #pragma unroll
        for (int kc = 0; kc < 4; ++kc) {
            bf16x8 bfr = *(const bf16x8*)(bb + nt * 16 * HID + kc * 32);
            acc[nt] = __builtin_amdgcn_mfma_f32_16x16x32_bf16(af[kc], bfr, acc[nt], 0, 0, 0);
        }
    }

    float p0 = 0.f, p1 = 0.f, p2 = 0.f, p3 = 0.f;
    #pragma unroll
    for (int nt = 0; nt < 8; ++nt) {
        int c = nt * 16 + mrow;
        float b1v = b1[c], w2v = W2[c];
        p0 += fmaxf(acc[nt][0] + b1v, 0.f) * w2v;
        p1 += fmaxf(acc[nt][1] + b1v, 0.f) * w2v;
        p2 += fmaxf(acc[nt][2] + b1v, 0.f) * w2v;
        p3 += fmaxf(acc[nt][3] + b1v, 0.f) * w2v;
    }
    #pragma unroll
    for (int off = 1; off < 16; off <<= 1) {
        p0 += __shfl_xor(p0, off);
        p1 += __shfl_xor(p1, off);
        p2 += __shfl_xor(p2, off);
        p3 += __shfl_xor(p3, off);
    }
    if (mrow == 0) {
        int rb = w * 16 + quad * 4;
        sred[rb + 0] = p0;
        sred[rb + 1] = p1;
        sred[rb + 2] = p2;
        sred[rb + 3] = p3;
    }
    __syncthreads();

    if (t < 64) {
        int grow = row0 + t;
        float s = sred[t] + b2[0];
        if (grow < N) scores[grow] = s;
        else s = -1e30f;

        float mmax = s;
        int midx = grow;
        #pragma unroll
        for (int off = 1; off < 64; off <<= 1) {
            float om = __shfl_xor(mmax, off);
            int oi = __shfl_xor(midx, off);
            if (om > mmax || (om == mmax && oi < midx)) { mmax = om; midx = oi; }
        }
        float d = s - mmax;
        float e = expf(d);
        float z = e;
        float ss = d * e;
        #pragma unroll
        for (int off = 1; off < 64; off <<= 1) {
            z += __shfl_xor(z, off);
            ss += __shfl_xor(ss, off);
        }
        if (t == 0)
            partials[blockIdx.x] = make_float4(mmax, z, ss, (float)midx);
    }
}

// ---------------------------------------------------------------------------
__device__ inline void sm_merge(float& am, float& az, float& ass, int& ai,
                                float bm, float bz, float bss, int bi)
{
    if (bm > am || (bm == am && bi < ai)) {
        float tm = am, tz = az, ts = ass; int ti = ai;
        am = bm; az = bz; ass = bss; ai = bi;
        bm = tm; bz = tz; bss = ts; bi = ti;
    }
    float f = expf(bm - am);
    az += bz * f;
    ass += (bss + (bm - am) * bz) * f;
}

// ---------------------------------------------------------------------------
// K3 (1 block): merge partials -> mhat, Z; out[3] = entropy. (R2/R6-validated)
// ---------------------------------------------------------------------------
__global__ __launch_bounds__(1024) void merge_kernel(
    const float4* __restrict__ partials, int nparts,
    float* __restrict__ statsf, float* __restrict__ out)
{
    __shared__ float4 wred[16];
    __shared__ int widx[16];
    const int t = threadIdx.x;
    const int w = t >> 6;
    const int l = t & 63;

    float m = -1e30f, z = 0.f, ss = 0.f;
    int idx = 0x7fffffff;
    for (int i = t; i < nparts; i += 1024) {
        float4 p = partials[i];
        sm_merge(m, z, ss, idx, p.x, p.y, p.z, (int)p.w);
    }
    #pragma unroll
    for (int off = 1; off < 64; off <<= 1) {
        float om = __shfl_xor(m, off);
        float oz = __shfl_xor(z, off);
        float os = __shfl_xor(ss, off);
        int oi = __shfl_xor(idx, off);
        sm_merge(m, z, ss, idx, om, oz, os, oi);
    }
    if (l == 0) { wred[w] = make_float4(m, z, ss, 0.f); widx[w] = idx; }
    __syncthreads();
    if (t == 0) {
        for (int i = 1; i < 16; ++i)
            sm_merge(m, z, ss, idx, wred[i].x, wred[i].y, wred[i].z, widx[i]);
        out[3] = logf(z) - ss / z;      // entropy
        statsf[0] = m;                  // mhat
        statsf[1] = z;                  // Z (relative to mhat)
    }
}

// ---------------------------------------------------------------------------
// K4 (ceil(N/256) blocks x 256): block b scans rows [256b,256b+256).
//   Per-block candidate count is structurally <= 256 — overflow impossible
//   (R4/R5 failure class eliminated by construction). Exact fp32 rescore of
//   local candidates (R6-validated register+shfl routine, 1 wave/candidate),
//   per-block best -> bests[b] = {score, idx}.
// ---------------------------------------------------------------------------
__global__ __launch_bounds__(256) void scan_kernel(
    const float* __restrict__ scores,
    const float* __restrict__ statsf,
    const int* __restrict__ m_ids,
    const int* __restrict__ job_idx,
    const float* __restrict__ x_m,
    const float* __restrict__ x_job,
    const float* __restrict__ W0,
    const float* __restrict__ W1,
    const float* __restrict__ b1,
    const float* __restrict__ W2,
    const float* __restrict__ b2,
    const float* __restrict__ g,
    float2* __restrict__ bests,
    int N)
{
    __shared__ int cand[256];
    __shared__ int ccount;
    __shared__ float rs[4];
    __shared__ int ri[4];

    const int t = threadIdx.x;
    const int w = t >> 6;
    const int l = t & 63;
    const int base = blockIdx.x * 256;

    if (t == 0) ccount = 0;
    __syncthreads();

    const float cut = statsf[0] - DELTA;
    int i = base + t;
    if (i < N && scores[i] >= cut) {
        int p = atomicAdd(&ccount, 1);  // LDS atomic; p < 256 guaranteed
        cand[p] = i;
    }
    __syncthreads();
    const int nc = ccount;
    if (nc == 0) {
        if (t == 0) bests[blockIdx.x] = make_float2(-1e30f, __int_as_float(0x7fffffff));
        return;
    }

    float bs = -1e30f;
    int bi = 0x7fffffff;
    for (int c = w; c < nc; c += 4) {
        int gr = cand[c];
        int mm = m_ids[gr];
        int jj = job_idx[gr];
        const float* xm = x_m + (size_t)mm * HID;
        const float* xj = x_job + (size_t)jj * HID;
        const float* wm = W0 + 2 * HID * HID;
        const float* wj = W0 + 3 * HID * HID;
        float a0 = g[l], a1 = g[l + 64];
        for (int k = 0; k < HID; ++k) {
            float xmk = xm[k];
            float xjk = xj[k];
            a0 = fmaf(xmk, wm[k * HID + l], a0);
            a1 = fmaf(xmk, wm[k * HID + l + 64], a1);
            a0 = fmaf(xjk, wj[k * HID + l], a0);
            a1 = fmaf(xjk, wj[k * HID + l + 64], a1);
        }
        a0 = fmaxf(a0, 0.f);
        a1 = fmaxf(a1, 0.f);
        float acc0 = 0.f, acc1 = 0.f;
        for (int k = 0; k < 64; ++k) {
            float h = __shfl(a0, k);
            acc0 = fmaf(h, W1[k * HID + l], acc0);
            acc1 = fmaf(h, W1[k * HID + l + 64], acc1);
        }
        for (int k = 0; k < 64; ++k) {
            float h = __shfl(a1, k);
            acc0 = fmaf(h, W1[(k + 64) * HID + l], acc0);
            acc1 = fmaf(h, W1[(k + 64) * HID + l + 64], acc1);
        }
        float p = fmaxf(acc0 + b1[l], 0.f) * W2[l]
                + fmaxf(acc1 + b1[l + 64], 0.f) * W2[l + 64];
        #pragma unroll
        for (int off = 1; off < 64; off <<= 1)
            p += __shfl_xor(p, off);
        float s = p + b2[0];
        if (s > bs || (s == bs && gr < bi)) { bs = s; bi = gr; }
    }
    if (l == 0) { rs[w] = bs; ri[w] = bi; }
    __syncthreads();
    if (t == 0) {
        float best = rs[0];
        int bwin = ri[0];
        for (int i2 = 1; i2 < 4; ++i2)
            if (rs[i2] > best || (rs[i2] == best && ri[i2] < bwin)) {
                best = rs[i2]; bwin = ri[i2];
            }
        bests[blockIdx.x] = make_float2(best, __int_as_float(bwin));
    }
}

// ---------------------------------------------------------------------------
// K5 (1 block): merge per-block bests -> out[0..2]. Min-idx tie-break.
// ---------------------------------------------------------------------------
__global__ __launch_bounds__(256) void finalize_kernel(
    const float2* __restrict__ bests, int nblocks,
    const float* __restrict__ statsf,
    float* __restrict__ out)
{
    __shared__ float rs[4];
    __shared__ int ri[4];
    const int t = threadIdx.x;
    const int w = t >> 6;
    const int l = t & 63;

    float bs = -1e30f;
    int bi = 0x7fffffff;
    for (int i = t; i < nblocks; i += 256) {
        float2 b = bests[i];
        int gi = __float_as_int(b.y);
        if (b.x > bs || (b.x == bs && gi < bi)) { bs = b.x; bi = gi; }
    }
    #pragma unroll
    for (int off = 1; off < 64; off <<= 1) {
        float os = __shfl_xor(bs, off);
        int oi = __shfl_xor(bi, off);
        if (os > bs || (os == bs && oi < bi)) { bs = os; bi = oi; }
    }
    if (l == 0) { rs[w] = bs; ri[w] = bi; }
    __syncthreads();
    if (t == 0) {
        for (int i = 1; i < 4; ++i)
            if (rs[i] > bs || (rs[i] == bs && ri[i] < bi)) { bs = rs[i]; bi = ri[i]; }
        float mhat = statsf[0], Z = statsf[1];
        out[0] = (float)bi;
        out[1] = expf(bs - mhat) / Z;
        out[2] = (bs - mhat) - logf(Z);
    }
}

// ---------------------------------------------------------------------------
extern "C" void kernel_launch(void* const* d_in, const int* in_sizes, int n_in,
                              void* d_out, int out_size, void* d_ws, size_t ws_size,
                              hipStream_t stream)
{
    const float* x_graph = (const float*)d_in[0];
    const float* x_m     = (const float*)d_in[1];
    const float* x_job   = (const float*)d_in[2];
    const int*   m_ids   = (const int*)d_in[3];
    const int*   job_idx = (const int*)d_in[4];
    const float* W0      = (const float*)d_in[5];
    const float* b0      = (const float*)d_in[6];
    const float* W1      = (const float*)d_in[7];
    const float* b1      = (const float*)d_in[8];
    const float* W2      = (const float*)d_in[9];
    const float* b2      = (const float*)d_in[10];
    float* out = (float*)d_out;

    const int N = in_sizes[3];
    const int M = in_sizes[1] / HID;
    const int J = in_sizes[2] / HID;

    const int tiles = (N + TILE_R - 1) / TILE_R;         // 3125
    const int aTiles = (M + TILE_R - 1) / TILE_R;        // 16
    const int bTiles = (J + TILE_R - 1) / TILE_R;        // 79
    const int sblocks = (N + 255) / 256;                 // 782

    // ws layout (all segments 16-B aligned):
    float* ws = (float*)d_ws;
    float* g = ws;                                        // 128 f
    float* scores = ws + HID;                             // N f
    float4* partials = (float4*)(scores + N);             // tiles f4
    float* statsf = (float*)(partials + tiles);           // 4 f
    float2* bests = (float2*)(statsf + 4);                // sblocks f2
    unsigned short* W1T = (unsigned short*)(bests + sblocks + (sblocks & 1)); // HID*HID shorts
    unsigned short* Pbf = W1T + HID * HID;                // (M+J)*HID shorts

    precompute_kernel<<<1 + aTiles + bTiles + 1, 256, 0, stream>>>(
        x_graph, x_m, x_job, W0, b0, W1, g, Pbf, W1T, M, J, aTiles, bTiles);
    main_kernel<<<tiles, 256, 0, stream>>>(
        m_ids, job_idx, b1, W2, b2, g, Pbf, W1T, scores, partials, N, M);
    merge_kernel<<<1, 1024, 0, stream>>>(partials, tiles, statsf, out);
    scan_kernel<<<sblocks, 256, 0, stream>>>(
        scores, statsf, m_ids, job_idx, x_m, x_job, W0, W1, b1, W2, b2, g,
        bests, N);
    finalize_kernel<<<1, 256, 0, stream>>>(bests, sblocks, statsf, out);
}

// Round 8
// 155.101 us; speedup vs baseline: 1.6507x; 1.2202x over previous
//
#include <hip/hip_runtime.h>
#include <math.h>

#define HID 128
#define TILE_R 64
#define XS_STRIDE 132      // fp32 staging stride (K1)
#define H0S_STRIDE 136     // bf16 LDS stride in shorts: 272 B = 68 dwords == 4 mod 32 banks
#define DELTA 0.05f        // per-score qualify margin (R3/R6-validated)

typedef short bf16x8 __attribute__((ext_vector_type(8)));
typedef float f32x4 __attribute__((ext_vector_type(4)));

static __device__ __forceinline__ unsigned short f2bf(float f) {
    union { float f; unsigned u; } v; v.f = f;
    unsigned r = v.u + 0x7FFFu + ((v.u >> 16) & 1u);   // RNE
    return (unsigned short)(r >> 16);
}
static __device__ __forceinline__ float bflo(unsigned u) {
    union { unsigned u; float f; } v; v.u = u << 16; return v.f;
}
static __device__ __forceinline__ float bfhi(unsigned u) {
    union { unsigned u; float f; } v; v.u = u & 0xFFFF0000u; return v.f;
}

#define FMA4(avc, wv)                         \
    acc[r][0] = fmaf(avc, wv.x, acc[r][0]);   \
    acc[r][1] = fmaf(avc, wv.y, acc[r][1]);   \
    acc[r][2] = fmaf(avc, wv.z, acc[r][2]);   \
    acc[r][3] = fmaf(avc, wv.w, acc[r][3]);

// ---------------------------------------------------------------------------
// K1: g[128] = x_graph @ W0[0:256] + b0 (fp32, exact)
//     Pbf = bf16( [x_m @ W0[256:384] ; x_job @ W0[384:512]] )
//     W1T[n*128+k] = bf16(W1[k][n])
// ---------------------------------------------------------------------------
__global__ __launch_bounds__(256, 4) void precompute_kernel(
    const float* __restrict__ x_graph,
    const float* __restrict__ x_m,
    const float* __restrict__ x_job,
    const float* __restrict__ W0,
    const float* __restrict__ b0,
    const float* __restrict__ W1,
    float* __restrict__ g,
    unsigned short* __restrict__ Pbf,
    unsigned short* __restrict__ W1T,
    int M, int J, int aTiles, int bTiles)
{
    const int t = threadIdx.x;
    const int bid = blockIdx.x;

    if (bid == 0) {
        __shared__ float xg[2 * HID];
        if (t < HID) { xg[t] = x_graph[t]; xg[t + HID] = x_graph[t + HID]; }
        __syncthreads();
        if (t < HID) {
            float acc = b0[t];
            #pragma unroll 8
            for (int k = 0; k < 2 * HID; ++k)
                acc = fmaf(xg[k], W0[k * HID + t], acc);
            g[t] = acc;
        }
        return;
    }
    if (bid == 1 + aTiles + bTiles) {
        for (int e = t; e < HID * HID; e += 256) {
            int n = e >> 7, k = e & 127;
            W1T[e] = f2bf(W1[k * HID + n]);
        }
        return;
    }

    const int tb = bid - 1;
    const float* X;
    const float* W;
    int r0, nr, dstBase;
    if (tb < aTiles) {
        r0 = tb * TILE_R;
        nr = min(TILE_R, M - r0);
        X = x_m + (size_t)r0 * HID;
        W = W0 + 2 * HID * HID;
        dstBase = r0;
    } else {
        int jb = tb - aTiles;
        r0 = jb * TILE_R;
        nr = min(TILE_R, J - r0);
        X = x_job + (size_t)r0 * HID;
        W = W0 + 3 * HID * HID;
        dstBase = M + r0;
    }

    __shared__ float xs[TILE_R * XS_STRIDE];
    {
        int row = t >> 2;
        int q = t & 3;
        #pragma unroll
        for (int u = 0; u < 8; ++u) {
            int c = q * 32 + u * 4;
            float4 v = (row < nr) ? *(const float4*)(X + row * HID + c)
                                  : make_float4(0.f, 0.f, 0.f, 0.f);
            *(float4*)&xs[row * XS_STRIDE + c] = v;
        }
    }
    __syncthreads();

    const int w = t >> 6;
    const int l = t & 63;
    const int tc = l & 7;
    const int tr = l >> 3;
    const int c0 = w * 32 + tc * 4;

    float acc[8][4];
    #pragma unroll
    for (int r = 0; r < 8; ++r)
        #pragma unroll
        for (int c = 0; c < 4; ++c) acc[r][c] = 0.0f;

    #pragma unroll 2
    for (int k0 = 0; k0 < HID; k0 += 4) {
        float4 w0v = *(const float4*)(W + (k0 + 0) * HID + c0);
        float4 w1v = *(const float4*)(W + (k0 + 1) * HID + c0);
        float4 w2m = *(const float4*)(W + (k0 + 2) * HID + c0);
        float4 w3v = *(const float4*)(W + (k0 + 3) * HID + c0);
        #pragma unroll
        for (int r = 0; r < 8; ++r) {
            float4 a = *(const float4*)&xs[(r * 8 + tr) * XS_STRIDE + k0];
            FMA4(a.x, w0v)
            FMA4(a.y, w1v)
            FMA4(a.z, w2m)
            FMA4(a.w, w3v)
        }
    }

    #pragma unroll
    for (int r = 0; r < 8; ++r) {
        int row = r * 8 + tr;
        if (row < nr) {
            unsigned lo0 = (unsigned)f2bf(acc[r][0]) | ((unsigned)f2bf(acc[r][1]) << 16);
            unsigned lo1 = (unsigned)f2bf(acc[r][2]) | ((unsigned)f2bf(acc[r][3]) << 16);
            uint2 pk = make_uint2(lo0, lo1);
            *(uint2*)(Pbf + (size_t)(dstBase + row) * HID + c0) = pk;
        }
    }
}

// ---------------------------------------------------------------------------
// K2: per 64-row tile. W1T staged in LDS once per block (R7 fix: global B
//     fragment loads with VGPR=48 left no room to pipeline -> 32-deep serial
//     L2-latency chain per wave = the 72us stall). bf16 h0 in LDS, h1 via
//     mfma_f32_16x16x32_bf16, fused epilogue -> scores + block partial.
// ---------------------------------------------------------------------------
__global__ __launch_bounds__(256, 3) void main_kernel(
    const int* __restrict__ m_ids,
    const int* __restrict__ job_idx,
    const float* __restrict__ b1,
    const float* __restrict__ W2,
    const float* __restrict__ b2,
    const float* __restrict__ g,
    const unsigned short* __restrict__ Pbf,
    const unsigned short* __restrict__ W1T,
    float* __restrict__ scores,
    float4* __restrict__ partials,
    int N, int M)
{
    __shared__ __align__(16) short h0s[TILE_R * H0S_STRIDE];
    __shared__ __align__(16) short w1s[HID * H0S_STRIDE];
    __shared__ float sred[TILE_R];

    const int t = threadIdx.x;
    const int row0 = blockIdx.x * TILE_R;

    // ---- stage W1T -> LDS (coalesced, independent: issue FIRST so it
    //      overlaps the dependent idx->gather chain below) ----
    {
        const uint4* src = (const uint4*)W1T;        // 2048 x 16B
        #pragma unroll
        for (int e = t; e < 2048; e += 256) {
            int n = e >> 4, pos = e & 15;
            *(uint4*)&w1s[n * H0S_STRIDE + pos * 8] = src[e];
        }
    }

    // ---- stage h0 (bf16): thread t -> row t/4, 32-col quarter t%4 ----
    {
        int row = t >> 2;
        int q = t & 3;
        int grow = row0 + row;
        int gr = (grow < N) ? grow : (N - 1);
        int m = m_ids[gr];
        int j = job_idx[gr];
        const unsigned short* pm = Pbf + (size_t)m * HID + q * 32;
        const unsigned short* pj = Pbf + (size_t)(M + j) * HID + q * 32;
        const float* gp = g + q * 32;
        short* dst = &h0s[row * H0S_STRIDE + q * 32];
        #pragma unroll
        for (int u = 0; u < 4; ++u) {
            uint4 mv = *(const uint4*)(pm + u * 8);
            uint4 jv = *(const uint4*)(pj + u * 8);
            float4 g0 = *(const float4*)(gp + u * 8);
            float4 g1 = *(const float4*)(gp + u * 8 + 4);
            float h0v = fmaxf(bflo(mv.x) + bflo(jv.x) + g0.x, 0.f);
            float h1v = fmaxf(bfhi(mv.x) + bfhi(jv.x) + g0.y, 0.f);
            float h2v = fmaxf(bflo(mv.y) + bflo(jv.y) + g0.z, 0.f);
            float h3v = fmaxf(bfhi(mv.y) + bfhi(jv.y) + g0.w, 0.f);
            float h4v = fmaxf(bflo(mv.z) + bflo(jv.z) + g1.x, 0.f);
            float h5v = fmaxf(bfhi(mv.z) + bfhi(jv.z) + g1.y, 0.f);
            float h6v = fmaxf(bflo(mv.w) + bflo(jv.w) + g1.z, 0.f);
            float h7v = fmaxf(bfhi(mv.w) + bfhi(jv.w) + g1.w, 0.f);
            uint4 pk;
            pk.x = (unsigned)f2bf(h0v) | ((unsigned)f2bf(h1v) << 16);
            pk.y = (unsigned)f2bf(h2v) | ((unsigned)f2bf(h3v) << 16);
            pk.z = (unsigned)f2bf(h4v) | ((unsigned)f2bf(h5v) << 16);
            pk.w = (unsigned)f2bf(h6v) | ((unsigned)f2bf(h7v) << 16);
            *(uint4*)(dst + u * 8) = pk;
        }
    }
    __syncthreads();

    // ---- MFMA: wave w computes rows [w*16, w*16+16) x cols [0,128) ----
    const int l = t & 63;
    const int w = t >> 6;
    const int quad = l >> 4;
    const int mrow = l & 15;

    bf16x8 af[4];
    const short* ab = &h0s[(w * 16 + mrow) * H0S_STRIDE + quad * 8];
    #pragma unroll
    for (int kc = 0; kc < 4; ++kc)
        af[kc] = *(const bf16x8*)(ab + kc * 32);

    f32x4 acc[8];
    #pragma unroll
    for (int nt = 0; nt < 8; ++nt) {
        f32x4 z = {0.f, 0.f, 0.f, 0.f};
        acc[nt] = z;
    }

    const short* bb = &w1s[mrow * H0S_STRIDE + quad * 8];
    #pragma unroll
    for (int nt = 0; nt < 8; ++nt) {
        #pragma unroll
        for (int kc = 0; kc < 4; ++kc) {
            bf16x8 bfr = *(const bf16x8*)(bb + nt * 16 * H0S_STRIDE + kc * 32);
            acc[nt] = __builtin_amdgcn_mfma_f32_16x16x32_bf16(af[kc], bfr, acc[nt], 0, 0, 0);
        }
    }

    // ---- epilogue: relu+b1, dot W2; reduce across the 16 col-lanes ----
    float p0 = 0.f, p1 = 0.f, p2 = 0.f, p3 = 0.f;
    #pragma unroll
    for (int nt = 0; nt < 8; ++nt) {
        int c = nt * 16 + mrow;
        float b1v = b1[c], w2v = W2[c];
        p0 += fmaxf(acc[nt][0] + b1v, 0.f) * w2v;
        p1 += fmaxf(acc[nt][1] + b1v, 0.f) * w2v;
        p2 += fmaxf(acc[nt][2] + b1v, 0.f) * w2v;
        p3 += fmaxf(acc[nt][3] + b1v, 0.f) * w2v;
    }
    #pragma unroll
    for (int off = 1; off < 16; off <<= 1) {
        p0 += __shfl_xor(p0, off);
        p1 += __shfl_xor(p1, off);
        p2 += __shfl_xor(p2, off);
        p3 += __shfl_xor(p3, off);
    }
    if (mrow == 0) {
        int rb = w * 16 + quad * 4;
        sred[rb + 0] = p0;
        sred[rb + 1] = p1;
        sred[rb + 2] = p2;
        sred[rb + 3] = p3;
    }
    __syncthreads();

    if (t < 64) {
        int grow = row0 + t;
        float s = sred[t] + b2[0];
        if (grow < N) scores[grow] = s;
        else s = -1e30f;

        float mmax = s;
        int midx = grow;
        #pragma unroll
        for (int off = 1; off < 64; off <<= 1) {
            float om = __shfl_xor(mmax, off);
            int oi = __shfl_xor(midx, off);
            if (om > mmax || (om == mmax && oi < midx)) { mmax = om; midx = oi; }
        }
        float d = s - mmax;
        float e = expf(d);
        float z = e;
        float ss = d * e;
        #pragma unroll
        for (int off = 1; off < 64; off <<= 1) {
            z += __shfl_xor(z, off);
            ss += __shfl_xor(ss, off);
        }
        if (t == 0)
            partials[blockIdx.x] = make_float4(mmax, z, ss, (float)midx);
    }
}

// ---------------------------------------------------------------------------
__device__ inline void sm_merge(float& am, float& az, float& ass, int& ai,
                                float bm, float bz, float bss, int bi)
{
    if (bm > am || (bm == am && bi < ai)) {
        float tm = am, tz = az, ts = ass; int ti = ai;
        am = bm; az = bz; ass = bss; ai = bi;
        bm = tm; bz = tz; bss = ts; bi = ti;
    }
    float f = expf(bm - am);
    az += bz * f;
    ass += (bss + (bm - am) * bz) * f;
}

// ---------------------------------------------------------------------------
// K3 (1 block): merge partials -> mhat, Z; out[3] = entropy.
// ---------------------------------------------------------------------------
__global__ __launch_bounds__(1024) void merge_kernel(
    const float4* __restrict__ partials, int nparts,
    float* __restrict__ statsf, float* __restrict__ out)
{
    __shared__ float4 wred[16];
    __shared__ int widx[16];
    const int t = threadIdx.x;
    const int w = t >> 6;
    const int l = t & 63;

    float m = -1e30f, z = 0.f, ss = 0.f;
    int idx = 0x7fffffff;
    for (int i = t; i < nparts; i += 1024) {
        float4 p = partials[i];
        sm_merge(m, z, ss, idx, p.x, p.y, p.z, (int)p.w);
    }
    #pragma unroll
    for (int off = 1; off < 64; off <<= 1) {
        float om = __shfl_xor(m, off);
        float oz = __shfl_xor(z, off);
        float os = __shfl_xor(ss, off);
        int oi = __shfl_xor(idx, off);
        sm_merge(m, z, ss, idx, om, oz, os, oi);
    }
    if (l == 0) { wred[w] = make_float4(m, z, ss, 0.f); widx[w] = idx; }
    __syncthreads();
    if (t == 0) {
        for (int i = 1; i < 16; ++i)
            sm_merge(m, z, ss, idx, wred[i].x, wred[i].y, wred[i].z, widx[i]);
        out[3] = logf(z) - ss / z;      // entropy
        statsf[0] = m;                  // mhat
        statsf[1] = z;                  // Z (relative to mhat)
    }
}

// ---------------------------------------------------------------------------
// K4 (ceil(N/256) blocks x 256): block b scans rows [256b,256b+256).
//   Per-block candidate count structurally <= 256 — no overflow possible.
//   Exact fp32 rescore of local candidates (register+shfl, R6-validated),
//   per-block best -> bests[b].
// ---------------------------------------------------------------------------
__global__ __launch_bounds__(256) void scan_kernel(
    const float* __restrict__ scores,
    const float* __restrict__ statsf,
    const int* __restrict__ m_ids,
    const int* __restrict__ job_idx,
    const float* __restrict__ x_m,
    const float* __restrict__ x_job,
    const float* __restrict__ W0,
    const float* __restrict__ W1,
    const float* __restrict__ b1,
    const float* __restrict__ W2,
    const float* __restrict__ b2,
    const float* __restrict__ g,
    float2* __restrict__ bests,
    int N)
{
    __shared__ int cand[256];
    __shared__ int ccount;
    __shared__ float rs[4];
    __shared__ int ri[4];

    const int t = threadIdx.x;
    const int w = t >> 6;
    const int l = t & 63;
    const int base = blockIdx.x * 256;

    if (t == 0) ccount = 0;
    __syncthreads();

    const float cut = statsf[0] - DELTA;
    int i = base + t;
    if (i < N && scores[i] >= cut) {
        int p = atomicAdd(&ccount, 1);  // LDS atomic; p < 256 guaranteed
        cand[p] = i;
    }
    __syncthreads();
    const int nc = ccount;
    if (nc == 0) {
        if (t == 0) bests[blockIdx.x] = make_float2(-1e30f, __int_as_float(0x7fffffff));
        return;
    }

    float bs = -1e30f;
    int bi = 0x7fffffff;
    for (int c = w; c < nc; c += 4) {
        int gr = cand[c];
        int mm = m_ids[gr];
        int jj = job_idx[gr];
        const float* xm = x_m + (size_t)mm * HID;
        const float* xj = x_job + (size_t)jj * HID;
        const float* wm = W0 + 2 * HID * HID;
        const float* wj = W0 + 3 * HID * HID;
        float a0 = g[l], a1 = g[l + 64];
        for (int k = 0; k < HID; ++k) {
            float xmk = xm[k];
            float xjk = xj[k];
            a0 = fmaf(xmk, wm[k * HID + l], a0);
            a1 = fmaf(xmk, wm[k * HID + l + 64], a1);
            a0 = fmaf(xjk, wj[k * HID + l], a0);
            a1 = fmaf(xjk, wj[k * HID + l + 64], a1);
        }
        a0 = fmaxf(a0, 0.f);
        a1 = fmaxf(a1, 0.f);
        float acc0 = 0.f, acc1 = 0.f;
        for (int k = 0; k < 64; ++k) {
            float h = __shfl(a0, k);
            acc0 = fmaf(h, W1[k * HID + l], acc0);
            acc1 = fmaf(h, W1[k * HID + l + 64], acc1);
        }
        for (int k = 0; k < 64; ++k) {
            float h = __shfl(a1, k);
            acc0 = fmaf(h, W1[(k + 64) * HID + l], acc0);
            acc1 = fmaf(h, W1[(k + 64) * HID + l + 64], acc1);
        }
        float p = fmaxf(acc0 + b1[l], 0.f) * W2[l]
                + fmaxf(acc1 + b1[l + 64], 0.f) * W2[l + 64];
        #pragma unroll
        for (int off = 1; off < 64; off <<= 1)
            p += __shfl_xor(p, off);
        float s = p + b2[0];
        if (s > bs || (s == bs && gr < bi)) { bs = s; bi = gr; }
    }
    if (l == 0) { rs[w] = bs; ri[w] = bi; }
    __syncthreads();
    if (t == 0) {
        float best = rs[0];
        int bwin = ri[0];
        for (int i2 = 1; i2 < 4; ++i2)
            if (rs[i2] > best || (rs[i2] == best && ri[i2] < bwin)) {
                best = rs[i2]; bwin = ri[i2];
            }
        bests[blockIdx.x] = make_float2(best, __int_as_float(bwin));
    }
}

// ---------------------------------------------------------------------------
// K5 (1 block): merge per-block bests -> out[0..2]. Min-idx tie-break.
// ---------------------------------------------------------------------------
__global__ __launch_bounds__(256) void finalize_kernel(
    const float2* __restrict__ bests, int nblocks,
    const float* __restrict__ statsf,
    float* __restrict__ out)
{
    __shared__ float rs[4];
    __shared__ int ri[4];
    const int t = threadIdx.x;
    const int w = t >> 6;
    const int l = t & 63;

    float bs = -1e30f;
    int bi = 0x7fffffff;
    for (int i = t; i < nblocks; i += 256) {
        float2 b = bests[i];
        int gi = __float_as_int(b.y);
        if (b.x > bs || (b.x == bs && gi < bi)) { bs = b.x; bi = gi; }
    }
    #pragma unroll
    for (int off = 1; off < 64; off <<= 1) {
        float os = __shfl_xor(bs, off);
        int oi = __shfl_xor(bi, off);
        if (os > bs || (os == bs && oi < bi)) { bs = os; bi = oi; }
    }
    if (l == 0) { rs[w] = bs; ri[w] = bi; }
    __syncthreads();
    if (t == 0) {
        for (int i = 1; i < 4; ++i)
            if (rs[i] > bs || (rs[i] == bs && ri[i] < bi)) { bs = rs[i]; bi = ri[i]; }
        float mhat = statsf[0], Z = statsf[1];
        out[0] = (float)bi;
        out[1] = expf(bs - mhat) / Z;
        out[2] = (bs - mhat) - logf(Z);
    }
}

// ---------------------------------------------------------------------------
extern "C" void kernel_launch(void* const* d_in, const int* in_sizes, int n_in,
                              void* d_out, int out_size, void* d_ws, size_t ws_size,
                              hipStream_t stream)
{
    const float* x_graph = (const float*)d_in[0];
    const float* x_m     = (const float*)d_in[1];
    const float* x_job   = (const float*)d_in[2];
    const int*   m_ids   = (const int*)d_in[3];
    const int*   job_idx = (const int*)d_in[4];
    const float* W0      = (const float*)d_in[5];
    const float* b0      = (const float*)d_in[6];
    const float* W1      = (const float*)d_in[7];
    const float* b1      = (const float*)d_in[8];
    const float* W2      = (const float*)d_in[9];
    const float* b2      = (const float*)d_in[10];
    float* out = (float*)d_out;

    const int N = in_sizes[3];
    const int M = in_sizes[1] / HID;
    const int J = in_sizes[2] / HID;

    const int tiles = (N + TILE_R - 1) / TILE_R;         // 3125
    const int aTiles = (M + TILE_R - 1) / TILE_R;        // 16
    const int bTiles = (J + TILE_R - 1) / TILE_R;        // 79
    const int sblocks = (N + 255) / 256;                 // 782

    // ws layout (all segments 16-B aligned):
    float* ws = (float*)d_ws;
    float* g = ws;                                        // 128 f
    float* scores = ws + HID;                             // N f
    float4* partials = (float4*)(scores + N);             // tiles f4
    float* statsf = (float*)(partials + tiles);           // 4 f
    float2* bests = (float2*)(statsf + 4);                // sblocks f2
    unsigned short* W1T = (unsigned short*)(bests + sblocks + (sblocks & 1)); // HID*HID shorts
    unsigned short* Pbf = W1T + HID * HID;                // (M+J)*HID shorts

    precompute_kernel<<<1 + aTiles + bTiles + 1, 256, 0, stream>>>(
        x_graph, x_m, x_job, W0, b0, W1, g, Pbf, W1T, M, J, aTiles, bTiles);
    main_kernel<<<tiles, 256, 0, stream>>>(
        m_ids, job_idx, b1, W2, b2, g, Pbf, W1T, scores, partials, N, M);
    merge_kernel<<<1, 1024, 0, stream>>>(partials, tiles, statsf, out);
    scan_kernel<<<sblocks, 256, 0, stream>>>(
        scores, statsf, m_ids, job_idx, x_m, x_job, W0, W1, b1, W2, b2, g,
        bests, N);
    finalize_kernel<<<1, 256, 0, stream>>>(bests, sblocks, statsf, out);
}

// Round 9
// 144.983 us; speedup vs baseline: 1.7659x; 1.0698x over previous
//
#include <hip/hip_runtime.h>
#include <math.h>

#define HID 128
#define TILE_R 64
#define TILE_P 32          // precompute row tile (R8: 97 blocks left 60% of CUs idle)
#define XS_STRIDE 132      // fp32 staging stride (K1)
#define H0S_STRIDE 136     // bf16 LDS stride in shorts: 272 B = 68 dwords == 4 mod 32 banks
#define DELTA 0.05f        // per-score qualify margin (R3/R6-validated)

typedef short bf16x8 __attribute__((ext_vector_type(8)));
typedef float f32x4 __attribute__((ext_vector_type(4)));

static __device__ __forceinline__ unsigned short f2bf(float f) {
    union { float f; unsigned u; } v; v.f = f;
    unsigned r = v.u + 0x7FFFu + ((v.u >> 16) & 1u);   // RNE
    return (unsigned short)(r >> 16);
}
static __device__ __forceinline__ float bflo(unsigned u) {
    union { unsigned u; float f; } v; v.u = u << 16; return v.f;
}
static __device__ __forceinline__ float bfhi(unsigned u) {
    union { unsigned u; float f; } v; v.u = u & 0xFFFF0000u; return v.f;
}

#define FMA4(avc, wv)                         \
    acc[r][0] = fmaf(avc, wv.x, acc[r][0]);   \
    acc[r][1] = fmaf(avc, wv.y, acc[r][1]);   \
    acc[r][2] = fmaf(avc, wv.z, acc[r][2]);   \
    acc[r][3] = fmaf(avc, wv.w, acc[r][3]);

// ---------------------------------------------------------------------------
// K1: g[128] = x_graph @ W0[0:256] + b0 (fp32, exact)
//     Pbf = bf16( [x_m @ W0[256:384] ; x_job @ W0[384:512]] )   (32-row tiles)
//     W1T[n*128+k] = bf16(W1[k][n])
// ---------------------------------------------------------------------------
__global__ __launch_bounds__(256, 4) void precompute_kernel(
    const float* __restrict__ x_graph,
    const float* __restrict__ x_m,
    const float* __restrict__ x_job,
    const float* __restrict__ W0,
    const float* __restrict__ b0,
    const float* __restrict__ W1,
    float* __restrict__ g,
    unsigned short* __restrict__ Pbf,
    unsigned short* __restrict__ W1T,
    int M, int J, int aTiles, int bTiles)
{
    const int t = threadIdx.x;
    const int bid = blockIdx.x;

    if (bid == 0) {
        __shared__ float xg[2 * HID];
        if (t < HID) { xg[t] = x_graph[t]; xg[t + HID] = x_graph[t + HID]; }
        __syncthreads();
        if (t < HID) {
            float acc = b0[t];
            #pragma unroll 8
            for (int k = 0; k < 2 * HID; ++k)
                acc = fmaf(xg[k], W0[k * HID + t], acc);
            g[t] = acc;
        }
        return;
    }
    if (bid == 1 + aTiles + bTiles) {
        for (int e = t; e < HID * HID; e += 256) {
            int n = e >> 7, k = e & 127;
            W1T[e] = f2bf(W1[k * HID + n]);
        }
        return;
    }

    const int tb = bid - 1;
    const float* X;
    const float* W;
    int r0, nr, dstBase;
    if (tb < aTiles) {
        r0 = tb * TILE_P;
        nr = min(TILE_P, M - r0);
        X = x_m + (size_t)r0 * HID;
        W = W0 + 2 * HID * HID;
        dstBase = r0;
    } else {
        int jb = tb - aTiles;
        r0 = jb * TILE_P;
        nr = min(TILE_P, J - r0);
        X = x_job + (size_t)r0 * HID;
        W = W0 + 3 * HID * HID;
        dstBase = M + r0;
    }

    __shared__ float xs[TILE_P * XS_STRIDE];
    {
        int row = t >> 3;           // 0..31
        int e = t & 7;              // 16-col eighth
        #pragma unroll
        for (int u = 0; u < 4; ++u) {
            int c = e * 16 + u * 4;
            float4 v = (row < nr) ? *(const float4*)(X + row * HID + c)
                                  : make_float4(0.f, 0.f, 0.f, 0.f);
            *(float4*)&xs[row * XS_STRIDE + c] = v;
        }
    }
    __syncthreads();

    const int w = t >> 6;
    const int l = t & 63;
    const int tc = l & 7;
    const int tr = l >> 3;
    const int c0 = w * 32 + tc * 4;

    float acc[4][4];
    #pragma unroll
    for (int r = 0; r < 4; ++r)
        #pragma unroll
        for (int c = 0; c < 4; ++c) acc[r][c] = 0.0f;

    #pragma unroll 2
    for (int k0 = 0; k0 < HID; k0 += 4) {
        float4 w0v = *(const float4*)(W + (k0 + 0) * HID + c0);
        float4 w1v = *(const float4*)(W + (k0 + 1) * HID + c0);
        float4 w2m = *(const float4*)(W + (k0 + 2) * HID + c0);
        float4 w3v = *(const float4*)(W + (k0 + 3) * HID + c0);
        #pragma unroll
        for (int r = 0; r < 4; ++r) {
            float4 a = *(const float4*)&xs[(r * 8 + tr) * XS_STRIDE + k0];
            FMA4(a.x, w0v)
            FMA4(a.y, w1v)
            FMA4(a.z, w2m)
            FMA4(a.w, w3v)
        }
    }

    #pragma unroll
    for (int r = 0; r < 4; ++r) {
        int row = r * 8 + tr;
        if (row < nr) {
            unsigned lo0 = (unsigned)f2bf(acc[r][0]) | ((unsigned)f2bf(acc[r][1]) << 16);
            unsigned lo1 = (unsigned)f2bf(acc[r][2]) | ((unsigned)f2bf(acc[r][3]) << 16);
            uint2 pk = make_uint2(lo0, lo1);
            *(uint2*)(Pbf + (size_t)(dstBase + row) * HID + c0) = pk;
        }
    }
}

// ---------------------------------------------------------------------------
// K2: per 64-row tile. W1T staged in LDS once per block (R7-validated fix).
//     bf16 h0 in LDS, h1 via mfma_f32_16x16x32_bf16, fused epilogue ->
//     scores[] + per-block softmax partial. No global atomics/fences.
// ---------------------------------------------------------------------------
__global__ __launch_bounds__(256, 3) void main_kernel(
    const int* __restrict__ m_ids,
    const int* __restrict__ job_idx,
    const float* __restrict__ b1,
    const float* __restrict__ W2,
    const float* __restrict__ b2,
    const float* __restrict__ g,
    const unsigned short* __restrict__ Pbf,
    const unsigned short* __restrict__ W1T,
    float* __restrict__ scores,
    float4* __restrict__ partials,
    int N, int M)
{
    __shared__ __align__(16) short h0s[TILE_R * H0S_STRIDE];
    __shared__ __align__(16) short w1s[HID * H0S_STRIDE];
    __shared__ float sred[TILE_R];

    const int t = threadIdx.x;
    const int row0 = blockIdx.x * TILE_R;

    // ---- stage W1T -> LDS first (independent; overlaps idx->gather chain) ----
    {
        const uint4* src = (const uint4*)W1T;        // 2048 x 16B
        #pragma unroll
        for (int e = t; e < 2048; e += 256) {
            int n = e >> 4, pos = e & 15;
            *(uint4*)&w1s[n * H0S_STRIDE + pos * 8] = src[e];
        }
    }

    // ---- stage h0 (bf16): thread t -> row t/4, 32-col quarter t%4 ----
    {
        int row = t >> 2;
        int q = t & 3;
        int grow = row0 + row;
        int gr = (grow < N) ? grow : (N - 1);
        int m = m_ids[gr];
        int j = job_idx[gr];
        const unsigned short* pm = Pbf + (size_t)m * HID + q * 32;
        const unsigned short* pj = Pbf + (size_t)(M + j) * HID + q * 32;
        const float* gp = g + q * 32;
        short* dst = &h0s[row * H0S_STRIDE + q * 32];
        #pragma unroll
        for (int u = 0; u < 4; ++u) {
            uint4 mv = *(const uint4*)(pm + u * 8);
            uint4 jv = *(const uint4*)(pj + u * 8);
            float4 g0 = *(const float4*)(gp + u * 8);
            float4 g1 = *(const float4*)(gp + u * 8 + 4);
            float h0v = fmaxf(bflo(mv.x) + bflo(jv.x) + g0.x, 0.f);
            float h1v = fmaxf(bfhi(mv.x) + bfhi(jv.x) + g0.y, 0.f);
            float h2v = fmaxf(bflo(mv.y) + bflo(jv.y) + g0.z, 0.f);
            float h3v = fmaxf(bfhi(mv.y) + bfhi(jv.y) + g0.w, 0.f);
            float h4v = fmaxf(bflo(mv.z) + bflo(jv.z) + g1.x, 0.f);
            float h5v = fmaxf(bfhi(mv.z) + bfhi(jv.z) + g1.y, 0.f);
            float h6v = fmaxf(bflo(mv.w) + bflo(jv.w) + g1.z, 0.f);
            float h7v = fmaxf(bfhi(mv.w) + bfhi(jv.w) + g1.w, 0.f);
            uint4 pk;
            pk.x = (unsigned)f2bf(h0v) | ((unsigned)f2bf(h1v) << 16);
            pk.y = (unsigned)f2bf(h2v) | ((unsigned)f2bf(h3v) << 16);
            pk.z = (unsigned)f2bf(h4v) | ((unsigned)f2bf(h5v) << 16);
            pk.w = (unsigned)f2bf(h6v) | ((unsigned)f2bf(h7v) << 16);
            *(uint4*)(dst + u * 8) = pk;
        }
    }
    __syncthreads();

    // ---- MFMA: wave w computes rows [w*16, w*16+16) x cols [0,128) ----
    const int l = t & 63;
    const int w = t >> 6;
    const int quad = l >> 4;
    const int mrow = l & 15;

    bf16x8 af[4];
    const short* ab = &h0s[(w * 16 + mrow) * H0S_STRIDE + quad * 8];
    #pragma unroll
    for (int kc = 0; kc < 4; ++kc)
        af[kc] = *(const bf16x8*)(ab + kc * 32);

    f32x4 acc[8];
    #pragma unroll
    for (int nt = 0; nt < 8; ++nt) {
        f32x4 z = {0.f, 0.f, 0.f, 0.f};
        acc[nt] = z;
    }

    const short* bb = &w1s[mrow * H0S_STRIDE + quad * 8];
    #pragma unroll
    for (int nt = 0; nt < 8; ++nt) {
        #pragma unroll
        for (int kc = 0; kc < 4; ++kc) {
            bf16x8 bfr = *(const bf16x8*)(bb + nt * 16 * H0S_STRIDE + kc * 32);
            acc[nt] = __builtin_amdgcn_mfma_f32_16x16x32_bf16(af[kc], bfr, acc[nt], 0, 0, 0);
        }
    }

    // ---- epilogue: relu+b1, dot W2; reduce across the 16 col-lanes ----
    float p0 = 0.f, p1 = 0.f, p2 = 0.f, p3 = 0.f;
    #pragma unroll
    for (int nt = 0; nt < 8; ++nt) {
        int c = nt * 16 + mrow;
        float b1v = b1[c], w2v = W2[c];
        p0 += fmaxf(acc[nt][0] + b1v, 0.f) * w2v;
        p1 += fmaxf(acc[nt][1] + b1v, 0.f) * w2v;
        p2 += fmaxf(acc[nt][2] + b1v, 0.f) * w2v;
        p3 += fmaxf(acc[nt][3] + b1v, 0.f) * w2v;
    }
    #pragma unroll
    for (int off = 1; off < 16; off <<= 1) {
        p0 += __shfl_xor(p0, off);
        p1 += __shfl_xor(p1, off);
        p2 += __shfl_xor(p2, off);
        p3 += __shfl_xor(p3, off);
    }
    if (mrow == 0) {
        int rb = w * 16 + quad * 4;
        sred[rb + 0] = p0;
        sred[rb + 1] = p1;
        sred[rb + 2] = p2;
        sred[rb + 3] = p3;
    }
    __syncthreads();

    if (t < 64) {
        int grow = row0 + t;
        float s = sred[t] + b2[0];
        if (grow < N) scores[grow] = s;
        else s = -1e30f;

        float mmax = s;
        int midx = grow;
        #pragma unroll
        for (int off = 1; off < 64; off <<= 1) {
            float om = __shfl_xor(mmax, off);
            int oi = __shfl_xor(midx, off);
            if (om > mmax || (om == mmax && oi < midx)) { mmax = om; midx = oi; }
        }
        float d = s - mmax;
        float e = expf(d);
        float z = e;
        float ss = d * e;
        #pragma unroll
        for (int off = 1; off < 64; off <<= 1) {
            z += __shfl_xor(z, off);
            ss += __shfl_xor(ss, off);
        }
        if (t == 0)
            partials[blockIdx.x] = make_float4(mmax, z, ss, (float)midx);
    }
}

// ---------------------------------------------------------------------------
__device__ inline void sm_merge(float& am, float& az, float& ass, int& ai,
                                float bm, float bz, float bss, int bi)
{
    if (bm > am || (bm == am && bi < ai)) {
        float tm = am, tz = az, ts = ass; int ti = ai;
        am = bm; az = bz; ass = bss; ai = bi;
        bm = tm; bz = tz; bss = ts; bi = ti;
    }
    float f = expf(bm - am);
    az += bz * f;
    ass += (bss + (bm - am) * bz) * f;
}

// ---------------------------------------------------------------------------
// K3 (ceil(N/256) blocks x 256): fused merge+scan (kills one launch + the
//   statsf dependency hop). Each block derives the global cut LOCALLY:
//   cut = max(partials[].x) - DELTA  — a pure max, order-independent, so
//   every block computes the identical value. Then candidate scan of its own
//   256 rows (count structurally <= 256, no overflow), exact fp32 rescore
//   (register+shfl, R6-validated), per-block best -> bests[b].
// ---------------------------------------------------------------------------
__global__ __launch_bounds__(256) void scan_kernel(
    const float4* __restrict__ partials, int nparts,
    const float* __restrict__ scores,
    const int* __restrict__ m_ids,
    const int* __restrict__ job_idx,
    const float* __restrict__ x_m,
    const float* __restrict__ x_job,
    const float* __restrict__ W0,
    const float* __restrict__ W1,
    const float* __restrict__ b1,
    const float* __restrict__ W2,
    const float* __restrict__ b2,
    const float* __restrict__ g,
    float2* __restrict__ bests,
    int N)
{
    __shared__ int cand[256];
    __shared__ int ccount;
    __shared__ float rs[4];
    __shared__ int ri[4];
    __shared__ float mmx[4];

    const int t = threadIdx.x;
    const int w = t >> 6;
    const int l = t & 63;
    const int base = blockIdx.x * 256;

    // ---- local global-max over block partials (pure max: deterministic) ----
    float mhat = -1e30f;
    for (int i = t; i < nparts; i += 256)
        mhat = fmaxf(mhat, partials[i].x);
    #pragma unroll
    for (int off = 1; off < 64; off <<= 1)
        mhat = fmaxf(mhat, __shfl_xor(mhat, off));
    if (l == 0) mmx[w] = mhat;
    if (t == 0) ccount = 0;
    __syncthreads();
    mhat = fmaxf(fmaxf(mmx[0], mmx[1]), fmaxf(mmx[2], mmx[3]));
    const float cut = mhat - DELTA;

    // ---- candidate scan of this block's 256 rows ----
    int i = base + t;
    if (i < N && scores[i] >= cut) {
        int p = atomicAdd(&ccount, 1);  // LDS atomic; p < 256 guaranteed
        cand[p] = i;
    }
    __syncthreads();
    const int nc = ccount;
    if (nc == 0) {
        if (t == 0) bests[blockIdx.x] = make_float2(-1e30f, __int_as_float(0x7fffffff));
        return;
    }

    float bs = -1e30f;
    int bi = 0x7fffffff;
    for (int c = w; c < nc; c += 4) {
        int gr = cand[c];
        int mm = m_ids[gr];
        int jj = job_idx[gr];
        const float* xm = x_m + (size_t)mm * HID;
        const float* xj = x_job + (size_t)jj * HID;
        const float* wm = W0 + 2 * HID * HID;
        const float* wj = W0 + 3 * HID * HID;
        float a0 = g[l], a1 = g[l + 64];
        for (int k = 0; k < HID; ++k) {
            float xmk = xm[k];
            float xjk = xj[k];
            a0 = fmaf(xmk, wm[k * HID + l], a0);
            a1 = fmaf(xmk, wm[k * HID + l + 64], a1);
            a0 = fmaf(xjk, wj[k * HID + l], a0);
            a1 = fmaf(xjk, wj[k * HID + l + 64], a1);
        }
        a0 = fmaxf(a0, 0.f);
        a1 = fmaxf(a1, 0.f);
        float acc0 = 0.f, acc1 = 0.f;
        for (int k = 0; k < 64; ++k) {
            float h = __shfl(a0, k);
            acc0 = fmaf(h, W1[k * HID + l], acc0);
            acc1 = fmaf(h, W1[k * HID + l + 64], acc1);
        }
        for (int k = 0; k < 64; ++k) {
            float h = __shfl(a1, k);
            acc0 = fmaf(h, W1[(k + 64) * HID + l], acc0);
            acc1 = fmaf(h, W1[(k + 64) * HID + l + 64], acc1);
        }
        float p = fmaxf(acc0 + b1[l], 0.f) * W2[l]
                + fmaxf(acc1 + b1[l + 64], 0.f) * W2[l + 64];
        #pragma unroll
        for (int off = 1; off < 64; off <<= 1)
            p += __shfl_xor(p, off);
        float s = p + b2[0];
        if (s > bs || (s == bs && gr < bi)) { bs = s; bi = gr; }
    }
    if (l == 0) { rs[w] = bs; ri[w] = bi; }
    __syncthreads();
    if (t == 0) {
        float best = rs[0];
        int bwin = ri[0];
        for (int i2 = 1; i2 < 4; ++i2)
            if (rs[i2] > best || (rs[i2] == best && ri[i2] < bwin)) {
                best = rs[i2]; bwin = ri[i2];
            }
        bests[blockIdx.x] = make_float2(best, __int_as_float(bwin));
    }
}

// ---------------------------------------------------------------------------
// K4 (1 block): full softmax merge of partials (mhat, Z, SS) + merge of
//   per-block bests -> out[0..3]. Min-idx tie-break everywhere.
// ---------------------------------------------------------------------------
__global__ __launch_bounds__(256) void finalize_kernel(
    const float4* __restrict__ partials, int nparts,
    const float2* __restrict__ bests, int nblocks,
    float* __restrict__ out)
{
    __shared__ float4 wred[4];
    __shared__ int widx[4];
    __shared__ float rs[4];
    __shared__ int ri[4];
    const int t = threadIdx.x;
    const int w = t >> 6;
    const int l = t & 63;

    // softmax stats
    float m = -1e30f, z = 0.f, ss = 0.f;
    int idx = 0x7fffffff;
    for (int i = t; i < nparts; i += 256) {
        float4 p = partials[i];
        sm_merge(m, z, ss, idx, p.x, p.y, p.z, (int)p.w);
    }
    #pragma unroll
    for (int off = 1; off < 64; off <<= 1) {
        float om = __shfl_xor(m, off);
        float oz = __shfl_xor(z, off);
        float os = __shfl_xor(ss, off);
        int oi = __shfl_xor(idx, off);
        sm_merge(m, z, ss, idx, om, oz, os, oi);
    }
    if (l == 0) { wred[w] = make_float4(m, z, ss, 0.f); widx[w] = idx; }

    // exact winner from bests
    float bs = -1e30f;
    int bi = 0x7fffffff;
    for (int i = t; i < nblocks; i += 256) {
        float2 b = bests[i];
        int gi = __float_as_int(b.y);
        if (b.x > bs || (b.x == bs && gi < bi)) { bs = b.x; bi = gi; }
    }
    #pragma unroll
    for (int off = 1; off < 64; off <<= 1) {
        float os = __shfl_xor(bs, off);
        int oi = __shfl_xor(bi, off);
        if (os > bs || (os == bs && oi < bi)) { bs = os; bi = oi; }
    }
    if (l == 0) { rs[w] = bs; ri[w] = bi; }
    __syncthreads();

    if (t == 0) {
        for (int i = 1; i < 4; ++i) {
            sm_merge(m, z, ss, idx, wred[i].x, wred[i].y, wred[i].z, widx[i]);
            if (rs[i] > bs || (rs[i] == bs && ri[i] < bi)) { bs = rs[i]; bi = ri[i]; }
        }
        float logZ = logf(z);
        out[0] = (float)bi;             // exact argmax
        out[1] = expf(bs - m) / z;      // probs[idx]
        out[2] = (bs - m) - logZ;       // logp[idx]
        out[3] = logZ - ss / z;         // entropy
    }
}

// ---------------------------------------------------------------------------
extern "C" void kernel_launch(void* const* d_in, const int* in_sizes, int n_in,
                              void* d_out, int out_size, void* d_ws, size_t ws_size,
                              hipStream_t stream)
{
    const float* x_graph = (const float*)d_in[0];
    const float* x_m     = (const float*)d_in[1];
    const float* x_job   = (const float*)d_in[2];
    const int*   m_ids   = (const int*)d_in[3];
    const int*   job_idx = (const int*)d_in[4];
    const float* W0      = (const float*)d_in[5];
    const float* b0      = (const float*)d_in[6];
    const float* W1      = (const float*)d_in[7];
    const float* b1      = (const float*)d_in[8];
    const float* W2      = (const float*)d_in[9];
    const float* b2      = (const float*)d_in[10];
    float* out = (float*)d_out;

    const int N = in_sizes[3];
    const int M = in_sizes[1] / HID;
    const int J = in_sizes[2] / HID;

    const int tiles = (N + TILE_R - 1) / TILE_R;         // 3125
    const int aTiles = (M + TILE_P - 1) / TILE_P;        // 32
    const int bTiles = (J + TILE_P - 1) / TILE_P;        // 157
    const int sblocks = (N + 255) / 256;                 // 782

    // ws layout (all segments 16-B aligned):
    float* ws = (float*)d_ws;
    float* g = ws;                                        // 128 f
    float* scores = ws + HID;                             // N f
    float4* partials = (float4*)(scores + N);             // tiles f4
    float2* bests = (float2*)(partials + tiles);          // sblocks f2
    unsigned short* W1T = (unsigned short*)(bests + sblocks + (sblocks & 1)); // HID*HID shorts
    unsigned short* Pbf = W1T + HID * HID;                // (M+J)*HID shorts

    precompute_kernel<<<1 + aTiles + bTiles + 1, 256, 0, stream>>>(
        x_graph, x_m, x_job, W0, b0, W1, g, Pbf, W1T, M, J, aTiles, bTiles);
    main_kernel<<<tiles, 256, 0, stream>>>(
        m_ids, job_idx, b1, W2, b2, g, Pbf, W1T, scores, partials, N, M);
    scan_kernel<<<sblocks, 256, 0, stream>>>(
        partials, tiles, scores, m_ids, job_idx, x_m, x_job, W0, W1, b1, W2, b2,
        g, bests, N);
    finalize_kernel<<<1, 256, 0, stream>>>(partials, tiles, bests, sblocks, out);
}

// Round 10
// 141.102 us; speedup vs baseline: 1.8145x; 1.0275x over previous
//
#include <hip/hip_runtime.h>
#include <math.h>

#define HID 128
#define TILE_R 64
#define TILE_P 32          // precompute row tile
#define XS_STRIDE 132      // fp32 staging stride (K1)
#define H0S_STRIDE 136     // bf16 LDS stride in shorts: 272 B = 68 dwords == 4 mod 32 banks
#define DELTA 0.05f        // per-score qualify margin (R3/R6-validated)
#define MAIN_GRID 1042     // ceil(3125/3): grid-stride persistent main (R10)

typedef short bf16x8 __attribute__((ext_vector_type(8)));
typedef float f32x4 __attribute__((ext_vector_type(4)));

static __device__ __forceinline__ unsigned short f2bf(float f) {
    union { float f; unsigned u; } v; v.f = f;
    unsigned r = v.u + 0x7FFFu + ((v.u >> 16) & 1u);   // RNE
    return (unsigned short)(r >> 16);
}
static __device__ __forceinline__ float bflo(unsigned u) {
    union { unsigned u; float f; } v; v.u = u << 16; return v.f;
}
static __device__ __forceinline__ float bfhi(unsigned u) {
    union { unsigned u; float f; } v; v.u = u & 0xFFFF0000u; return v.f;
}

#define FMA4(avc, wv)                         \
    acc[r][0] = fmaf(avc, wv.x, acc[r][0]);   \
    acc[r][1] = fmaf(avc, wv.y, acc[r][1]);   \
    acc[r][2] = fmaf(avc, wv.z, acc[r][2]);   \
    acc[r][3] = fmaf(avc, wv.w, acc[r][3]);

// ---------------------------------------------------------------------------
// K1: g[128] = x_graph @ W0[0:256] + b0 (fp32, exact)
//     Pbf = bf16( [x_m @ W0[256:384] ; x_job @ W0[384:512]] )   (32-row tiles)
//     W1T[n*128+k] = bf16(W1[k][n])
// ---------------------------------------------------------------------------
__global__ __launch_bounds__(256, 4) void precompute_kernel(
    const float* __restrict__ x_graph,
    const float* __restrict__ x_m,
    const float* __restrict__ x_job,
    const float* __restrict__ W0,
    const float* __restrict__ b0,
    const float* __restrict__ W1,
    float* __restrict__ g,
    unsigned short* __restrict__ Pbf,
    unsigned short* __restrict__ W1T,
    int M, int J, int aTiles, int bTiles)
{
    const int t = threadIdx.x;
    const int bid = blockIdx.x;

    if (bid == 0) {
        __shared__ float xg[2 * HID];
        if (t < HID) { xg[t] = x_graph[t]; xg[t + HID] = x_graph[t + HID]; }
        __syncthreads();
        if (t < HID) {
            float acc = b0[t];
            #pragma unroll 8
            for (int k = 0; k < 2 * HID; ++k)
                acc = fmaf(xg[k], W0[k * HID + t], acc);
            g[t] = acc;
        }
        return;
    }
    if (bid == 1 + aTiles + bTiles) {
        for (int e = t; e < HID * HID; e += 256) {
            int n = e >> 7, k = e & 127;
            W1T[e] = f2bf(W1[k * HID + n]);
        }
        return;
    }

    const int tb = bid - 1;
    const float* X;
    const float* W;
    int r0, nr, dstBase;
    if (tb < aTiles) {
        r0 = tb * TILE_P;
        nr = min(TILE_P, M - r0);
        X = x_m + (size_t)r0 * HID;
        W = W0 + 2 * HID * HID;
        dstBase = r0;
    } else {
        int jb = tb - aTiles;
        r0 = jb * TILE_P;
        nr = min(TILE_P, J - r0);
        X = x_job + (size_t)r0 * HID;
        W = W0 + 3 * HID * HID;
        dstBase = M + r0;
    }

    __shared__ float xs[TILE_P * XS_STRIDE];
    {
        int row = t >> 3;           // 0..31
        int e = t & 7;              // 16-col eighth
        #pragma unroll
        for (int u = 0; u < 4; ++u) {
            int c = e * 16 + u * 4;
            float4 v = (row < nr) ? *(const float4*)(X + row * HID + c)
                                  : make_float4(0.f, 0.f, 0.f, 0.f);
            *(float4*)&xs[row * XS_STRIDE + c] = v;
        }
    }
    __syncthreads();

    const int w = t >> 6;
    const int l = t & 63;
    const int tc = l & 7;
    const int tr = l >> 3;
    const int c0 = w * 32 + tc * 4;

    float acc[4][4];
    #pragma unroll
    for (int r = 0; r < 4; ++r)
        #pragma unroll
        for (int c = 0; c < 4; ++c) acc[r][c] = 0.0f;

    #pragma unroll 2
    for (int k0 = 0; k0 < HID; k0 += 4) {
        float4 w0v = *(const float4*)(W + (k0 + 0) * HID + c0);
        float4 w1v = *(const float4*)(W + (k0 + 1) * HID + c0);
        float4 w2m = *(const float4*)(W + (k0 + 2) * HID + c0);
        float4 w3v = *(const float4*)(W + (k0 + 3) * HID + c0);
        #pragma unroll
        for (int r = 0; r < 4; ++r) {
            float4 a = *(const float4*)&xs[(r * 8 + tr) * XS_STRIDE + k0];
            FMA4(a.x, w0v)
            FMA4(a.y, w1v)
            FMA4(a.z, w2m)
            FMA4(a.w, w3v)
        }
    }

    #pragma unroll
    for (int r = 0; r < 4; ++r) {
        int row = r * 8 + tr;
        if (row < nr) {
            unsigned lo0 = (unsigned)f2bf(acc[r][0]) | ((unsigned)f2bf(acc[r][1]) << 16);
            unsigned lo1 = (unsigned)f2bf(acc[r][2]) | ((unsigned)f2bf(acc[r][3]) << 16);
            uint2 pk = make_uint2(lo0, lo1);
            *(uint2*)(Pbf + (size_t)(dstBase + row) * HID + c0) = pk;
        }
    }
}

// ---------------------------------------------------------------------------
// K2: grid-stride persistent (R10): each block stages W1T->LDS ONCE, then
//     loops over up to 3 tiles of 64 rows. Per tile: bf16 h0 gather -> LDS,
//     h1 via mfma_f32_16x16x32_bf16, fused epilogue -> scores + partial +
//     tmax. Barrier safety: af frags are in registers before barrier 2, so
//     h0s restaging after it is race-free. No global atomics/fences.
// ---------------------------------------------------------------------------
__global__ __launch_bounds__(256, 3) void main_kernel(
    const int* __restrict__ m_ids,
    const int* __restrict__ job_idx,
    const float* __restrict__ b1,
    const float* __restrict__ W2,
    const float* __restrict__ b2,
    const float* __restrict__ g,
    const unsigned short* __restrict__ Pbf,
    const unsigned short* __restrict__ W1T,
    float* __restrict__ scores,
    float4* __restrict__ partials,
    float* __restrict__ tmax,
    int N, int M, int tiles)
{
    __shared__ __align__(16) short h0s[TILE_R * H0S_STRIDE];
    __shared__ __align__(16) short w1s[HID * H0S_STRIDE];
    __shared__ float sred[TILE_R];

    const int t = threadIdx.x;
    const int l = t & 63;
    const int w = t >> 6;
    const int quad = l >> 4;
    const int mrow = l & 15;

    // ---- stage W1T -> LDS once per block ----
    {
        const uint4* src = (const uint4*)W1T;        // 2048 x 16B
        #pragma unroll
        for (int e = t; e < 2048; e += 256) {
            int n = e >> 4, pos = e & 15;
            *(uint4*)&w1s[n * H0S_STRIDE + pos * 8] = src[e];
        }
    }

    for (int tile = blockIdx.x; tile < tiles; tile += MAIN_GRID) {
        const int row0 = tile * TILE_R;

        // ---- stage h0 (bf16): thread t -> row t/4, 32-col quarter t%4 ----
        {
            int row = t >> 2;
            int q = t & 3;
            int grow = row0 + row;
            int gr = (grow < N) ? grow : (N - 1);
            int m = m_ids[gr];
            int j = job_idx[gr];
            const unsigned short* pm = Pbf + (size_t)m * HID + q * 32;
            const unsigned short* pj = Pbf + (size_t)(M + j) * HID + q * 32;
            const float* gp = g + q * 32;
            short* dst = &h0s[row * H0S_STRIDE + q * 32];
            #pragma unroll
            for (int u = 0; u < 4; ++u) {
                uint4 mv = *(const uint4*)(pm + u * 8);
                uint4 jv = *(const uint4*)(pj + u * 8);
                float4 g0 = *(const float4*)(gp + u * 8);
                float4 g1 = *(const float4*)(gp + u * 8 + 4);
                float h0v = fmaxf(bflo(mv.x) + bflo(jv.x) + g0.x, 0.f);
                float h1v = fmaxf(bfhi(mv.x) + bfhi(jv.x) + g0.y, 0.f);
                float h2v = fmaxf(bflo(mv.y) + bflo(jv.y) + g0.z, 0.f);
                float h3v = fmaxf(bfhi(mv.y) + bfhi(jv.y) + g0.w, 0.f);
                float h4v = fmaxf(bflo(mv.z) + bflo(jv.z) + g1.x, 0.f);
                float h5v = fmaxf(bfhi(mv.z) + bfhi(jv.z) + g1.y, 0.f);
                float h6v = fmaxf(bflo(mv.w) + bflo(jv.w) + g1.z, 0.f);
                float h7v = fmaxf(bfhi(mv.w) + bfhi(jv.w) + g1.w, 0.f);
                uint4 pk;
                pk.x = (unsigned)f2bf(h0v) | ((unsigned)f2bf(h1v) << 16);
                pk.y = (unsigned)f2bf(h2v) | ((unsigned)f2bf(h3v) << 16);
                pk.z = (unsigned)f2bf(h4v) | ((unsigned)f2bf(h5v) << 16);
                pk.w = (unsigned)f2bf(h6v) | ((unsigned)f2bf(h7v) << 16);
                *(uint4*)(dst + u * 8) = pk;
            }
        }
        __syncthreads();                       // barrier 1: h0s (+w1s, 1st iter) ready

        // ---- MFMA: wave w -> rows [w*16, w*16+16) x cols [0,128) ----
        bf16x8 af[4];
        const short* ab = &h0s[(w * 16 + mrow) * H0S_STRIDE + quad * 8];
        #pragma unroll
        for (int kc = 0; kc < 4; ++kc)
            af[kc] = *(const bf16x8*)(ab + kc * 32);

        f32x4 acc[8];
        #pragma unroll
        for (int nt = 0; nt < 8; ++nt) {
            f32x4 z = {0.f, 0.f, 0.f, 0.f};
            acc[nt] = z;
        }

        const short* bb = &w1s[mrow * H0S_STRIDE + quad * 8];
        #pragma unroll
        for (int nt = 0; nt < 8; ++nt) {
            #pragma unroll
            for (int kc = 0; kc < 4; ++kc) {
                bf16x8 bfr = *(const bf16x8*)(bb + nt * 16 * H0S_STRIDE + kc * 32);
                acc[nt] = __builtin_amdgcn_mfma_f32_16x16x32_bf16(af[kc], bfr, acc[nt], 0, 0, 0);
            }
        }

        // ---- epilogue: relu+b1, dot W2; reduce across the 16 col-lanes ----
        float p0 = 0.f, p1 = 0.f, p2 = 0.f, p3 = 0.f;
        #pragma unroll
        for (int nt = 0; nt < 8; ++nt) {
            int c = nt * 16 + mrow;
            float b1v = b1[c], w2v = W2[c];
            p0 += fmaxf(acc[nt][0] + b1v, 0.f) * w2v;
            p1 += fmaxf(acc[nt][1] + b1v, 0.f) * w2v;
            p2 += fmaxf(acc[nt][2] + b1v, 0.f) * w2v;
            p3 += fmaxf(acc[nt][3] + b1v, 0.f) * w2v;
        }
        #pragma unroll
        for (int off = 1; off < 16; off <<= 1) {
            p0 += __shfl_xor(p0, off);
            p1 += __shfl_xor(p1, off);
            p2 += __shfl_xor(p2, off);
            p3 += __shfl_xor(p3, off);
        }
        if (mrow == 0) {
            int rb = w * 16 + quad * 4;
            sred[rb + 0] = p0;
            sred[rb + 1] = p1;
            sred[rb + 2] = p2;
            sred[rb + 3] = p3;
        }
        __syncthreads();                       // barrier 2: sred ready; af in regs -> h0s free

        if (t < 64) {
            int grow = row0 + t;
            float s = sred[t] + b2[0];
            if (grow < N) scores[grow] = s;
            else s = -1e30f;

            float mmax = s;
            int midx = grow;
            #pragma unroll
            for (int off = 1; off < 64; off <<= 1) {
                float om = __shfl_xor(mmax, off);
                int oi = __shfl_xor(midx, off);
                if (om > mmax || (om == mmax && oi < midx)) { mmax = om; midx = oi; }
            }
            float d = s - mmax;
            float e = expf(d);
            float z = e;
            float ss = d * e;
            #pragma unroll
            for (int off = 1; off < 64; off <<= 1) {
                z += __shfl_xor(z, off);
                ss += __shfl_xor(ss, off);
            }
            if (t == 0) {
                partials[tile] = make_float4(mmax, z, ss, (float)midx);
                tmax[tile] = mmax;
            }
        }
    }
}

// ---------------------------------------------------------------------------
__device__ inline void sm_merge(float& am, float& az, float& ass, int& ai,
                                float bm, float bz, float bss, int bi)
{
    if (bm > am || (bm == am && bi < ai)) {
        float tm = am, tz = az, ts = ass; int ti = ai;
        am = bm; az = bz; ass = bss; ai = bi;
        bm = tm; bz = tz; bss = ts; bi = ti;
    }
    float f = expf(bm - am);
    az += bz * f;
    ass += (bss + (bm - am) * bz) * f;
}

// ---------------------------------------------------------------------------
// K3 (ceil(N/256) blocks x 256): fused merge+scan. Each block derives the
//   global cut LOCALLY from tmax[] (pure max — order-independent, identical
//   across blocks). Candidate scan of its own 256 rows (count <= 256 by
//   construction), exact fp32 rescore (register+shfl), best -> bests[b].
// ---------------------------------------------------------------------------
__global__ __launch_bounds__(256) void scan_kernel(
    const float* __restrict__ tmax, int nparts,
    const float* __restrict__ scores,
    const int* __restrict__ m_ids,
    const int* __restrict__ job_idx,
    const float* __restrict__ x_m,
    const float* __restrict__ x_job,
    const float* __restrict__ W0,
    const float* __restrict__ W1,
    const float* __restrict__ b1,
    const float* __restrict__ W2,
    const float* __restrict__ b2,
    const float* __restrict__ g,
    float2* __restrict__ bests,
    int N)
{
    __shared__ int cand[256];
    __shared__ int ccount;
    __shared__ float rs[4];
    __shared__ int ri[4];
    __shared__ float mmx[4];

    const int t = threadIdx.x;
    const int w = t >> 6;
    const int l = t & 63;
    const int base = blockIdx.x * 256;

    // ---- global max over tile maxima (4-way unrolled, pipelined loads) ----
    float m0 = -1e30f, m1 = -1e30f, m2 = -1e30f, m3 = -1e30f;
    int i = t;
    for (; i + 768 < nparts; i += 1024) {
        m0 = fmaxf(m0, tmax[i]);
        m1 = fmaxf(m1, tmax[i + 256]);
        m2 = fmaxf(m2, tmax[i + 512]);
        m3 = fmaxf(m3, tmax[i + 768]);
    }
    for (; i < nparts; i += 256) m0 = fmaxf(m0, tmax[i]);
    float mhat = fmaxf(fmaxf(m0, m1), fmaxf(m2, m3));
    #pragma unroll
    for (int off = 1; off < 64; off <<= 1)
        mhat = fmaxf(mhat, __shfl_xor(mhat, off));
    if (l == 0) mmx[w] = mhat;
    if (t == 0) ccount = 0;
    __syncthreads();
    mhat = fmaxf(fmaxf(mmx[0], mmx[1]), fmaxf(mmx[2], mmx[3]));
    const float cut = mhat - DELTA;

    // ---- candidate scan of this block's 256 rows ----
    int idx = base + t;
    if (idx < N && scores[idx] >= cut) {
        int p = atomicAdd(&ccount, 1);  // LDS atomic; p < 256 guaranteed
        cand[p] = idx;
    }
    __syncthreads();
    const int nc = ccount;
    if (nc == 0) {
        if (t == 0) bests[blockIdx.x] = make_float2(-1e30f, __int_as_float(0x7fffffff));
        return;
    }

    float bs = -1e30f;
    int bi = 0x7fffffff;
    for (int c = w; c < nc; c += 4) {
        int gr = cand[c];
        int mm = m_ids[gr];
        int jj = job_idx[gr];
        const float* xm = x_m + (size_t)mm * HID;
        const float* xj = x_job + (size_t)jj * HID;
        const float* wm = W0 + 2 * HID * HID;
        const float* wj = W0 + 3 * HID * HID;
        float a0 = g[l], a1 = g[l + 64];
        for (int k = 0; k < HID; ++k) {
            float xmk = xm[k];
            float xjk = xj[k];
            a0 = fmaf(xmk, wm[k * HID + l], a0);
            a1 = fmaf(xmk, wm[k * HID + l + 64], a1);
            a0 = fmaf(xjk, wj[k * HID + l], a0);
            a1 = fmaf(xjk, wj[k * HID + l + 64], a1);
        }
        a0 = fmaxf(a0, 0.f);
        a1 = fmaxf(a1, 0.f);
        float acc0 = 0.f, acc1 = 0.f;
        for (int k = 0; k < 64; ++k) {
            float h = __shfl(a0, k);
            acc0 = fmaf(h, W1[k * HID + l], acc0);
            acc1 = fmaf(h, W1[k * HID + l + 64], acc1);
        }
        for (int k = 0; k < 64; ++k) {
            float h = __shfl(a1, k);
            acc0 = fmaf(h, W1[(k + 64) * HID + l], acc0);
            acc1 = fmaf(h, W1[(k + 64) * HID + l + 64], acc1);
        }
        float p = fmaxf(acc0 + b1[l], 0.f) * W2[l]
                + fmaxf(acc1 + b1[l + 64], 0.f) * W2[l + 64];
        #pragma unroll
        for (int off = 1; off < 64; off <<= 1)
            p += __shfl_xor(p, off);
        float s = p + b2[0];
        if (s > bs || (s == bs && gr < bi)) { bs = s; bi = gr; }
    }
    if (l == 0) { rs[w] = bs; ri[w] = bi; }
    __syncthreads();
    if (t == 0) {
        float best = rs[0];
        int bwin = ri[0];
        for (int i2 = 1; i2 < 4; ++i2)
            if (rs[i2] > best || (rs[i2] == best && ri[i2] < bwin)) {
                best = rs[i2]; bwin = ri[i2];
            }
        bests[blockIdx.x] = make_float2(best, __int_as_float(bwin));
    }
}

// ---------------------------------------------------------------------------
// K4 (1 block): full softmax merge of partials + merge of per-block bests
//   -> out[0..3]. Min-idx tie-break everywhere.
// ---------------------------------------------------------------------------
__global__ __launch_bounds__(256) void finalize_kernel(
    const float4* __restrict__ partials, int nparts,
    const float2* __restrict__ bests, int nblocks,
    float* __restrict__ out)
{
    __shared__ float4 wred[4];
    __shared__ int widx[4];
    __shared__ float rs[4];
    __shared__ int ri[4];
    const int t = threadIdx.x;
    const int w = t >> 6;
    const int l = t & 63;

    float m = -1e30f, z = 0.f, ss = 0.f;
    int idx = 0x7fffffff;
    for (int i = t; i < nparts; i += 256) {
        float4 p = partials[i];
        sm_merge(m, z, ss, idx, p.x, p.y, p.z, (int)p.w);
    }
    #pragma unroll
    for (int off = 1; off < 64; off <<= 1) {
        float om = __shfl_xor(m, off);
        float oz = __shfl_xor(z, off);
        float os = __shfl_xor(ss, off);
        int oi = __shfl_xor(idx, off);
        sm_merge(m, z, ss, idx, om, oz, os, oi);
    }
    if (l == 0) { wred[w] = make_float4(m, z, ss, 0.f); widx[w] = idx; }

    float bs = -1e30f;
    int bi = 0x7fffffff;
    for (int i = t; i < nblocks; i += 256) {
        float2 b = bests[i];
        int gi = __float_as_int(b.y);
        if (b.x > bs || (b.x == bs && gi < bi)) { bs = b.x; bi = gi; }
    }
    #pragma unroll
    for (int off = 1; off < 64; off <<= 1) {
        float os = __shfl_xor(bs, off);
        int oi = __shfl_xor(bi, off);
        if (os > bs || (os == bs && oi < bi)) { bs = os; bi = oi; }
    }
    if (l == 0) { rs[w] = bs; ri[w] = bi; }
    __syncthreads();

    if (t == 0) {
        for (int i = 1; i < 4; ++i) {
            sm_merge(m, z, ss, idx, wred[i].x, wred[i].y, wred[i].z, widx[i]);
            if (rs[i] > bs || (rs[i] == bs && ri[i] < bi)) { bs = rs[i]; bi = ri[i]; }
        }
        float logZ = logf(z);
        out[0] = (float)bi;             // exact argmax
        out[1] = expf(bs - m) / z;      // probs[idx]
        out[2] = (bs - m) - logZ;       // logp[idx]
        out[3] = logZ - ss / z;         // entropy
    }
}

// ---------------------------------------------------------------------------
extern "C" void kernel_launch(void* const* d_in, const int* in_sizes, int n_in,
                              void* d_out, int out_size, void* d_ws, size_t ws_size,
                              hipStream_t stream)
{
    const float* x_graph = (const float*)d_in[0];
    const float* x_m     = (const float*)d_in[1];
    const float* x_job   = (const float*)d_in[2];
    const int*   m_ids   = (const int*)d_in[3];
    const int*   job_idx = (const int*)d_in[4];
    const float* W0      = (const float*)d_in[5];
    const float* b0      = (const float*)d_in[6];
    const float* W1      = (const float*)d_in[7];
    const float* b1      = (const float*)d_in[8];
    const float* W2      = (const float*)d_in[9];
    const float* b2      = (const float*)d_in[10];
    float* out = (float*)d_out;

    const int N = in_sizes[3];
    const int M = in_sizes[1] / HID;
    const int J = in_sizes[2] / HID;

    const int tiles = (N + TILE_R - 1) / TILE_R;         // 3125
    const int aTiles = (M + TILE_P - 1) / TILE_P;        // 32
    const int bTiles = (J + TILE_P - 1) / TILE_P;        // 157
    const int sblocks = (N + 255) / 256;                 // 782

    // ws layout (all segments 16-B aligned):
    float* ws = (float*)d_ws;
    float* g = ws;                                        // 128 f
    float* scores = ws + HID;                             // N f
    float4* partials = (float4*)(scores + N);             // tiles f4
    float* tmax = (float*)(partials + tiles);             // tiles f (padded)
    const int tmaxPad = (tiles + 3) & ~3;
    float2* bests = (float2*)(tmax + tmaxPad);            // sblocks f2
    unsigned short* W1T = (unsigned short*)(bests + sblocks + (sblocks & 1)); // HID*HID shorts
    unsigned short* Pbf = W1T + HID * HID;                // (M+J)*HID shorts

    precompute_kernel<<<1 + aTiles + bTiles + 1, 256, 0, stream>>>(
        x_graph, x_m, x_job, W0, b0, W1, g, Pbf, W1T, M, J, aTiles, bTiles);
    main_kernel<<<MAIN_GRID, 256, 0, stream>>>(
        m_ids, job_idx, b1, W2, b2, g, Pbf, W1T, scores, partials, tmax,
        N, M, tiles);
    scan_kernel<<<sblocks, 256, 0, stream>>>(
        tmax, tiles, scores, m_ids, job_idx, x_m, x_job, W0, W1, b1, W2, b2,
        g, bests, N);
    finalize_kernel<<<1, 256, 0, stream>>>(partials, tiles, bests, sblocks, out);
}